// Round 11
// baseline (1336.232 us; speedup 1.0000x reference)
//
#include <hip/hip_runtime.h>
#include <math.h>

#define OBS 8
#define SEQL 12
#define G 96
#define PP 16
#define B 1536
#define HD 128
#define ED 64
#define BOT 1024
#define MIDD 512
#define CTXD (HD + BOT)   /* 1152 */
#define MLPH 1024

typedef __attribute__((ext_vector_type(8))) short bf16x8;
typedef __attribute__((ext_vector_type(4))) float f32x4;

__device__ inline short f2bf(float x) {
    union { float f; unsigned u; } v; v.f = x;
    unsigned r = v.u + 0x7fffu + ((v.u >> 16) & 1u);   // RNE
    return (short)(r >> 16);
}

// ---------------------------------------------------------------------------
// setup kernels
// ---------------------------------------------------------------------------
// B-matrix -> MFMA-fragment-order bf16. src is (Nrows x Kcols) row-major fp32.
// dst unit u = (kt*NT + nt)*64 + lane: B[n=nt*16+(l&15)][k=kt*32+((l>>4)<<3)+e]
__global__ void swizzleB_kernel(const float* __restrict__ src, unsigned short* __restrict__ dst,
                                int NT, int K, int total) {
    int u = blockIdx.x * 256 + threadIdx.x;
    if (u >= total) return;
    int l = u & 63; int v = u >> 6; int nt = v % NT; int kt = v / NT;
    int n = nt * 16 + (l & 15);
    int k = kt * 32 + ((l >> 4) << 3);
    const float* s = src + n * K + k;
    float4 s0 = *(const float4*)s;
    float4 s1 = *(const float4*)(s + 4);
    bf16x8 o;
    o[0] = f2bf(s0.x); o[1] = f2bf(s0.y); o[2] = f2bf(s0.z); o[3] = f2bf(s0.w);
    o[4] = f2bf(s1.x); o[5] = f2bf(s1.y); o[6] = f2bf(s1.z); o[7] = f2bf(s1.w);
    *(bf16x8*)(dst + u * 8) = o;
}

// gates B = [W_ih | W_hh] (512 x 192) -> frag order (6 kt x 32 nt)
__global__ void swizzle_cat_kernel(const float* __restrict__ W_ih, const float* __restrict__ W_hh,
                                   unsigned short* __restrict__ dst) {
    int u = blockIdx.x * 256 + threadIdx.x;   // 6*32*64 = 12288 units
    if (u >= 6 * 32 * 64) return;
    int l = u & 63; int v = u >> 6; int nt = v & 31; int kt = v >> 5;
    int n = nt * 16 + (l & 15);
    int k0 = kt * 32 + ((l >> 4) << 3);
    bf16x8 o;
#pragma unroll
    for (int e = 0; e < 8; ++e) {
        int k = k0 + e;
        float val = (k < ED) ? W_ih[n * ED + k] : W_hh[n * HD + (k - ED)];
        o[e] = f2bf(val);
    }
    *(bf16x8*)(dst + u * 8) = o;
}

// u B-matrix = [Wp1_h | 0 | 0 | CV | 0pad] (512 x 160) -> frag order (5 kt x 32 nt)
__global__ void swizzle_p1_kernel(const float* __restrict__ Wp1,
                                  const float* __restrict__ CV,
                                  unsigned short* __restrict__ dst) {
    int u = blockIdx.x * 256 + threadIdx.x;   // 5*32*64 = 10240 units
    if (u >= 5 * 32 * 64) return;
    int l = u & 63; int v = u >> 6; int nt = v & 31; int kt = v >> 5;
    int n = nt * 16 + (l & 15);
    int k0 = kt * 32 + ((l >> 4) << 3);
    bf16x8 o;
#pragma unroll
    for (int e = 0; e < 8; ++e) {
        int k = k0 + e;
        float val;
        if (k < HD)           val = Wp1[n * (ED + HD) + ED + k];
        else if (k == HD + 2) val = CV[n];
        else                  val = 0.f;
        o[e] = f2bf(val);
    }
    *(bf16x8*)(dst + u * 8) = o;
}

// M = Wp1[:, :64] @ Wp_emb  (512x2), cvec = Wp1[:, :64] @ bp_emb + bp1
__global__ void mcvec_kernel(const float* __restrict__ Wp1, const float* __restrict__ Wp_emb,
                             const float* __restrict__ bp_emb, const float* __restrict__ bp1,
                             float* __restrict__ M0, float* __restrict__ M1, float* __restrict__ CV) {
    int r = blockIdx.x * blockDim.x + threadIdx.x;
    if (r >= MIDD) return;
    float m0 = 0.f, m1 = 0.f, cv = 0.f;
    for (int e = 0; e < ED; ++e) {
        float w = Wp1[r * (ED + HD) + e];
        m0 += w * Wp_emb[e * 2 + 0];
        m1 += w * Wp_emb[e * 2 + 1];
        cv += w * bp_emb[e];
    }
    M0[r] = m0; M1[r] = m1; CV[r] = cv + bp1[r];
}

// frag-order fp32 M tables: M0F[(kt*64+lane)*8+e] = M0[kt*32+(lane>>4)*8+e]
__global__ void m01f_kernel(const float* __restrict__ M0, const float* __restrict__ M1,
                            float* __restrict__ M0F, float* __restrict__ M1F) {
    int id = blockIdx.x * 256 + threadIdx.x;   // 16*64*8 = 8192
    if (id >= 16 * 64 * 8) return;
    int e = id & 7;
    int lane = (id >> 3) & 63;
    int kt = id >> 9;
    int k = kt * 32 + ((lane >> 4) << 3) + e;
    M0F[id] = M0[k];
    M1F[id] = M1[k];
}

__global__ void init_kernel(const float* __restrict__ obs_traj, const float* __restrict__ obs_traj_rel,
                            const float* __restrict__ h0, const float* __restrict__ c0,
                            const float* __restrict__ W_emb, const float* __restrict__ b_emb,
                            float* __restrict__ Hb, float* __restrict__ Cb,
                            float* __restrict__ POSb, float* __restrict__ DIN) {
    int b = blockIdx.x;
    int t = threadIdx.x; // 128
    Hb[b * HD + t] = h0[b * HD + t];
    Cb[b * HD + t] = c0[b * HD + t];
    if (t < 2) POSb[b * 2 + t] = obs_traj[((OBS - 1) * B + b) * 2 + t];
    if (t < ED) {
        float rx = obs_traj_rel[((OBS - 1) * B + b) * 2 + 0];
        float ry = obs_traj_rel[((OBS - 1) * B + b) * 2 + 1];
        DIN[b * ED + t] = W_emb[t * 2 + 0] * rx + W_emb[t * 2 + 1] * ry + b_emb[t];
    }
}

// ---------------------------------------------------------------------------
// fused step: gates MFMA -> LSTM cell (in-reg) -> rel_pos -> POS/DIN update ->
// u MFMA (u = Wp1h*h + CV, position-free). Block = one scene, 512 thr.
// Writes AbF (u) in MFMA A-fragment order (fp32).
// ---------------------------------------------------------------------------
__global__ __launch_bounds__(512) void step_kernel(
    const unsigned short* __restrict__ WcatF, const float* __restrict__ b_ih,
    const float* __restrict__ b_hh,
    const float* __restrict__ W_pos, const float* __restrict__ b_pos,
    const float* __restrict__ W_emb, const float* __restrict__ b_emb,
    const unsigned short* __restrict__ Wp1F2,
    float* __restrict__ Hb, float* __restrict__ Cb, float* __restrict__ POSb,
    float* __restrict__ DIN, unsigned short* __restrict__ Hbf,
    float* __restrict__ AbF, float* __restrict__ rel_out) {

    __shared__ unsigned short gf[6 * 64 * 8];    // gates A-frags, 6KB
    __shared__ unsigned short a2f[5 * 64 * 8];   // u A-frags, 5KB
    __shared__ float hsh[16 * HD];               // h_lstm, 8KB
    __shared__ float relsh[16][4];

    int gsc = blockIdx.x;          // scene
    int t = threadIdx.x;
    int lane = t & 63, w = t >> 6;
    int colid = lane & 15, quad = lane >> 4;

    // build gates A-frags: [din(64) | h_prev(128)], K=192 = 6 kt
    if (t < 384) {
        int kt = t >> 6;
        int j = lane & 15;
        int b = gsc * PP + j;
        int k0 = kt * 32 + ((lane >> 4) << 3);
        float4 x0, x1;
        if (k0 < ED) {
            const float4* p = (const float4*)(DIN + b * ED + k0);
            x0 = p[0]; x1 = p[1];
        } else {
            const float4* p = (const float4*)(Hb + b * HD + (k0 - ED));
            x0 = p[0]; x1 = p[1];
        }
        bf16x8 o;
        o[0] = f2bf(x0.x); o[1] = f2bf(x0.y); o[2] = f2bf(x0.z); o[3] = f2bf(x0.w);
        o[4] = f2bf(x1.x); o[5] = f2bf(x1.y); o[6] = f2bf(x1.z); o[7] = f2bf(x1.w);
        *(bf16x8*)(gf + t * 8) = o;
    }
    __syncthreads();

    // gates MFMA
    f32x4 acc[4];
#pragma unroll
    for (int gi = 0; gi < 4; ++gi) acc[gi] = (f32x4)0.f;
#pragma unroll
    for (int kt = 0; kt < 6; ++kt) {
        bf16x8 af = *(const bf16x8*)(gf + (kt * 64 + lane) * 8);
#pragma unroll
        for (int gi = 0; gi < 4; ++gi) {
            bf16x8 bfr = *(const bf16x8*)(WcatF + ((kt * 32 + gi * 8 + w) * 64 + lane) * 8);
            acc[gi] = __builtin_amdgcn_mfma_f32_16x16x32_bf16(af, bfr, acc[gi], 0, 0, 0);
        }
    }
    // LSTM cell, all four gates in-wave
    int hcol = w * 16 + colid;
    float bias[4];
#pragma unroll
    for (int gi = 0; gi < 4; ++gi) {
        int n = (gi * 8 + w) * 16 + colid;
        bias[gi] = b_ih[n] + b_hh[n];
    }
#pragma unroll
    for (int r = 0; r < 4; ++r) {
        int row = quad * 4 + r;
        int b = gsc * PP + row;
        float gI = acc[0][r] + bias[0];
        float gF = acc[1][r] + bias[1];
        float gG = acc[2][r] + bias[2];
        float gO = acc[3][r] + bias[3];
        float c = Cb[b * HD + hcol];
        float cn = (1.f / (1.f + expf(-gF))) * c + (1.f / (1.f + expf(-gI))) * tanhf(gG);
        float hn = (1.f / (1.f + expf(-gO))) * tanhf(cn);
        Cb[b * HD + hcol] = cn;
        Hbf[b * HD + hcol] = (unsigned short)f2bf(hn);
        hsh[row * HD + hcol] = hn;
    }
    __syncthreads();

    // rel_pos: 32 threads per row, shuffle reduce
    {
        int row = t >> 5, kk = t & 31;
        float r0 = 0.f, r1 = 0.f;
#pragma unroll
        for (int q = 0; q < 4; ++q) {
            int k = kk + q * 32;
            float hv = hsh[row * HD + k];
            r0 = fmaf(hv, W_pos[k], r0);
            r1 = fmaf(hv, W_pos[HD + k], r1);
        }
#pragma unroll
        for (int m = 16; m >= 1; m >>= 1) {
            r0 += __shfl_xor(r0, m, 64);
            r1 += __shfl_xor(r1, m, 64);
        }
        if (kk == 0) {
            int b = gsc * PP + row;
            r0 += b_pos[0]; r1 += b_pos[1];
            float px = POSb[b * 2 + 0] + r0;
            float py = POSb[b * 2 + 1] + r1;
            POSb[b * 2 + 0] = px; POSb[b * 2 + 1] = py;
            rel_out[b * 2 + 0] = r0; rel_out[b * 2 + 1] = r1;
            relsh[row][0] = r0; relsh[row][1] = r1; relsh[row][2] = px; relsh[row][3] = py;
        }
    }
    __syncthreads();

    // next dec_in
#pragma unroll
    for (int rep = 0; rep < 2; ++rep) {
        int idx = rep * 512 + t;
        int row = idx >> 6, e = idx & 63;
        int b = gsc * PP + row;
        DIN[b * ED + e] = W_emb[e * 2 + 0] * relsh[row][0] +
                          W_emb[e * 2 + 1] * relsh[row][1] + b_emb[e];
    }
    // u A-frags: [h(128) | 0 | 0 | 1 | 0pad], K=160 = 5 kt
    if (t < 320) {
        int kt = t >> 6;
        int j = lane & 15;
        int k0 = kt * 32 + ((lane >> 4) << 3);
        bf16x8 o;
#pragma unroll
        for (int e = 0; e < 8; ++e) {
            int k = k0 + e;
            float v;
            if (k < HD)            v = hsh[j * HD + k];
            else if (k == HD + 2)  v = 1.f;
            else                   v = 0.f;
            o[e] = f2bf(v);
        }
        *(bf16x8*)(a2f + t * 8) = o;
    }
    __syncthreads();

    // u MFMA: wave w -> nt = w*4+q (512 cols total); write AbF in frag order
    f32x4 acc2[4];
#pragma unroll
    for (int q = 0; q < 4; ++q) acc2[q] = (f32x4)0.f;
#pragma unroll
    for (int kt = 0; kt < 5; ++kt) {
        bf16x8 af = *(const bf16x8*)(a2f + (kt * 64 + lane) * 8);
#pragma unroll
        for (int q = 0; q < 4; ++q) {
            bf16x8 bfr = *(const bf16x8*)(Wp1F2 + ((kt * 32 + w * 4 + q) * 64 + lane) * 8);
            acc2[q] = __builtin_amdgcn_mfma_f32_16x16x32_bf16(af, bfr, acc2[q], 0, 0, 0);
        }
    }
#pragma unroll
    for (int q = 0; q < 4; ++q)
#pragma unroll
        for (int r = 0; r < 4; ++r) {
            int j = quad * 4 + r;                 // row within scene
            int k = (w * 4 + q) * 16 + colid;     // col (k-dim of pool GEMM)
            int kt2 = k >> 5, lk = (k >> 3) & 3, e = k & 7;
            AbF[((gsc * 16 + kt2) * 64 + lk * 16 + j) * 8 + e] = acc2[q][r];
        }
}

// ---------------------------------------------------------------------------
// pool_gemm10: LDS-staged streams (as gemm9) with two fixes:
//  (1) wave covers 2 i x 16 nt (acc 128 AGPR, launch_bounds(256,2)) — halves
//      the A-build VALU and LDS-read cost per MFMA (32 MFMA/kt/wave),
//  (2) u/M staged part-major as float4 @ 16B lane-stride — same bank pattern
//      as the (conflict-free) B reads, killing gemm9's 2.36M bank conflicts.
// grid = 96*2*4 = 768 blocks (g, io, colq): block = 8 i x 256 cols.
// ---------------------------------------------------------------------------
__global__ __launch_bounds__(256, 2) void pool_gemm10_kernel(
    const float* __restrict__ AbF, const float* __restrict__ POSb,
    const float* __restrict__ M0F, const float* __restrict__ M1F,
    const unsigned short* __restrict__ Wp2F, const float* __restrict__ bp2,
    unsigned short* __restrict__ POOLbf) {

    __shared__ __align__(16) unsigned short Bst[2][16 * 64 * 8];  // 2 x 16KB
    __shared__ __align__(16) float UMst[2][6][64 * 4];            // 2 x 6KB part-major

    int bi = blockIdx.x;
    int g = bi % 96;                 // scene -> XCD-local
    int rest = bi / 96;              // 0..7
    int io = rest >> 2;              // 0..1
    int colq = rest & 3;             // 0..3
    int t = threadIdx.x, lane = t & 63, w = t >> 6;
    int i0 = io * 8 + w * 2;
    int j = lane & 15;
    int ntb = colq * 16;

    float pjx = POSb[(g * PP + j) * 2 + 0];
    float pjy = POSb[(g * PP + j) * 2 + 1];
    float dx[2], dy[2];
#pragma unroll
    for (int p = 0; p < 2; ++p) {
        int gi = g * PP + i0 + p;
        dx[p] = pjx - POSb[gi * 2 + 0];
        dy[p] = pjy - POSb[gi * 2 + 1];
    }

    const float* ag = AbF + (size_t)g * (16 * 64 * 8);

    // stage streams for k-tile kt into buffer buf (all 256 threads)
    auto stage = [&](int kt, int buf) {
        // B: 16 nt x 64 lanes = 1024 units, 4 per thread
#pragma unroll
        for (int r = 0; r < 4; ++r) {
            int u = r * 256 + t;            // 0..1023
            int nt = u >> 6, l = u & 63;
            *(bf16x8*)&Bst[buf][u * 8] =
                *(const bf16x8*)(Wp2F + ((kt * 64 + ntb + nt) * 64 + l) * 8);
        }
        // u/M: 6 parts x 64 lanes, part-major float4 (16B lane stride)
        {
            int pt = t >> 6;                 // 0..3 (parts 0..3)
            int l = t & 63;
            const float* src = (pt < 2) ? (ag + kt * 512 + l * 8 + pt * 4)
                                        : (M0F + kt * 512 + l * 8 + (pt - 2) * 4);
            *(float4*)&UMst[buf][pt][l * 4] = *(const float4*)src;
            if (t < 128) {                   // parts 4..5 (M1F)
                int pt2 = 4 + (t >> 6);
                *(float4*)&UMst[buf][pt2][l * 4] =
                    *(const float4*)(M1F + kt * 512 + l * 8 + (t >> 6) * 4);
            }
        }
    };

    f32x4 acc[2][16];
#pragma unroll
    for (int p = 0; p < 2; ++p)
#pragma unroll
        for (int n = 0; n < 16; ++n) acc[p][n] = (f32x4)0.f;

    stage(0, 0);
    __syncthreads();

    for (int kt = 0; kt < 16; ++kt) {
        int buf = kt & 1;
        if (kt < 15) stage(kt + 1, buf ^ 1);

        float4 u0  = *(const float4*)&UMst[buf][0][lane * 4];
        float4 u1  = *(const float4*)&UMst[buf][1][lane * 4];
        float4 m00 = *(const float4*)&UMst[buf][2][lane * 4];
        float4 m01 = *(const float4*)&UMst[buf][3][lane * 4];
        float4 m10 = *(const float4*)&UMst[buf][4][lane * 4];
        float4 m11 = *(const float4*)&UMst[buf][5][lane * 4];

        bf16x8 af[2];
#pragma unroll
        for (int p = 0; p < 2; ++p) {
            float dxp = dx[p], dyp = dy[p];
            af[p][0] = f2bf(fmaxf(fmaf(m10.x, dyp, fmaf(m00.x, dxp, u0.x)), 0.f));
            af[p][1] = f2bf(fmaxf(fmaf(m10.y, dyp, fmaf(m00.y, dxp, u0.y)), 0.f));
            af[p][2] = f2bf(fmaxf(fmaf(m10.z, dyp, fmaf(m00.z, dxp, u0.z)), 0.f));
            af[p][3] = f2bf(fmaxf(fmaf(m10.w, dyp, fmaf(m00.w, dxp, u0.w)), 0.f));
            af[p][4] = f2bf(fmaxf(fmaf(m11.x, dyp, fmaf(m01.x, dxp, u1.x)), 0.f));
            af[p][5] = f2bf(fmaxf(fmaf(m11.y, dyp, fmaf(m01.y, dxp, u1.y)), 0.f));
            af[p][6] = f2bf(fmaxf(fmaf(m11.z, dyp, fmaf(m01.z, dxp, u1.z)), 0.f));
            af[p][7] = f2bf(fmaxf(fmaf(m11.w, dyp, fmaf(m01.w, dxp, u1.w)), 0.f));
        }
#pragma unroll
        for (int ng = 0; ng < 4; ++ng) {
            bf16x8 bfr[4];
#pragma unroll
            for (int n = 0; n < 4; ++n)
                bfr[n] = *(const bf16x8*)&Bst[buf][((ng * 4 + n) * 64 + lane) * 8];
#pragma unroll
            for (int n = 0; n < 4; ++n) {
                acc[0][ng * 4 + n] =
                    __builtin_amdgcn_mfma_f32_16x16x32_bf16(af[0], bfr[n], acc[0][ng * 4 + n], 0, 0, 0);
                acc[1][ng * 4 + n] =
                    __builtin_amdgcn_mfma_f32_16x16x32_bf16(af[1], bfr[n], acc[1][ng * 4 + n], 0, 0, 0);
            }
        }
        __syncthreads();   // staging of kt+1 done; reads of buf done
    }

    int quad = lane >> 4, colid = lane & 15;
#pragma unroll
    for (int p = 0; p < 2; ++p) {
        int i = g * PP + i0 + p;
#pragma unroll
        for (int n = 0; n < 16; ++n) {
            float m = fmaxf(fmaxf(acc[p][n][0], acc[p][n][1]),
                            fmaxf(acc[p][n][2], acc[p][n][3]));
            m = fmaxf(m, __shfl_xor(m, 16, 64));
            m = fmaxf(m, __shfl_xor(m, 32, 64));
            if (quad == 0) {
                int col = (ntb + n) * 16 + colid;
                float v = fmaxf(m + bp2[col], 0.f);
                POOLbf[i * BOT + col] = (unsigned short)f2bf(v);
            }
        }
    }
}

// ---------------------------------------------------------------------------
// MLP1 (MFMA): [Hbf | POOLbf] (1536x1152) @ Wm1F -> relu -> Y1Mbf (1536x1024)
// ---------------------------------------------------------------------------
__global__ __launch_bounds__(256) void mlp1_mfma_kernel(
    const unsigned short* __restrict__ Hbf, const unsigned short* __restrict__ POOLbf,
    const unsigned short* __restrict__ Wm1F, const float* __restrict__ bm1,
    unsigned short* __restrict__ Y1Mbf) {

    __shared__ unsigned short a_f[16 * 64 * 8];   // 16KB
    int mg = blockIdx.x;       // 0..23
    int ng = blockIdx.y;       // 0..15
    int t = threadIdx.x, lane = t & 63, w = t >> 6;
    int rh = w >> 1, nh = w & 1;

    f32x4 acc[2][2];
#pragma unroll
    for (int a = 0; a < 2; ++a)
#pragma unroll
        for (int b = 0; b < 2; ++b) acc[a][b] = (f32x4)0.f;

    for (int c = 0; c < 9; ++c) {
        __syncthreads();
#pragma unroll
        for (int u0 = 0; u0 < 1024; u0 += 256) {
            int u = u0 + t;
            int rg = u >> 8, kt = (u >> 6) & 3, l = u & 63;
            int row = mg * 64 + rg * 16 + (l & 15);
            int kl = kt * 32 + ((l >> 4) << 3);
            const unsigned short* src = (c == 0) ? (Hbf + row * HD + kl)
                                                 : (POOLbf + row * BOT + (c - 1) * 128 + kl);
            *(bf16x8*)(a_f + u * 8) = *(const bf16x8*)src;
        }
        __syncthreads();
#pragma unroll
        for (int kt = 0; kt < 4; ++kt) {
            int ktg = c * 4 + kt;
            bf16x8 bfr[2];
#pragma unroll
            for (int j = 0; j < 2; ++j) {
                int ntg = ng * 4 + nh * 2 + j;
                bfr[j] = *(const bf16x8*)(Wm1F + ((ktg * 64 + ntg) * 64 + lane) * 8);
            }
#pragma unroll
            for (int ri = 0; ri < 2; ++ri) {
                int rg = rh * 2 + ri;
                bf16x8 af = *(const bf16x8*)(a_f + ((rg * 4 + kt) * 64 + lane) * 8);
#pragma unroll
                for (int j = 0; j < 2; ++j)
                    acc[ri][j] = __builtin_amdgcn_mfma_f32_16x16x32_bf16(af, bfr[j], acc[ri][j], 0, 0, 0);
            }
        }
    }
    int quad = lane >> 4, colid = lane & 15;
#pragma unroll
    for (int ri = 0; ri < 2; ++ri)
#pragma unroll
        for (int j = 0; j < 2; ++j) {
            int col = ng * 64 + (nh * 2 + j) * 16 + colid;
            float bb = bm1[col];
#pragma unroll
            for (int r = 0; r < 4; ++r) {
                int row = mg * 64 + (rh * 2 + ri) * 16 + quad * 4 + r;
                float v = fmaxf(acc[ri][j][r] + bb, 0.f);
                Y1Mbf[row * MLPH + col] = (unsigned short)f2bf(v);
            }
        }
}

// ---------------------------------------------------------------------------
// MLP2 (MFMA): Y1Mbf (1536x1024) @ Wm2F -> relu -> Hb fp32 (and h_out last step)
// ---------------------------------------------------------------------------
__global__ __launch_bounds__(256) void mlp2_mfma_kernel(
    const unsigned short* __restrict__ Y1Mbf, const unsigned short* __restrict__ Wm2F,
    const float* __restrict__ bm2, float* __restrict__ Hb, float* __restrict__ hout) {

    __shared__ unsigned short a_f[32 * 64 * 8];   // 32KB
    int rg = blockIdx.x;   // 0..95
    int t = threadIdx.x, lane = t & 63, w = t >> 6;

#pragma unroll
    for (int u0 = 0; u0 < 2048; u0 += 256) {
        int u = u0 + t;
        int kt = u >> 6, l = u & 63;
        int row = rg * 16 + (l & 15);
        int kl = kt * 32 + ((l >> 4) << 3);
        *(bf16x8*)(a_f + u * 8) = *(const bf16x8*)(Y1Mbf + row * MLPH + kl);
    }
    __syncthreads();

    f32x4 acc[2];
    acc[0] = (f32x4)0.f; acc[1] = (f32x4)0.f;
    for (int kt = 0; kt < 32; ++kt) {
        bf16x8 af = *(const bf16x8*)(a_f + (kt * 64 + lane) * 8);
#pragma unroll
        for (int j = 0; j < 2; ++j) {
            int ntg = w * 2 + j;
            bf16x8 bfr = *(const bf16x8*)(Wm2F + ((kt * 8 + ntg) * 64 + lane) * 8);
            acc[j] = __builtin_amdgcn_mfma_f32_16x16x32_bf16(af, bfr, acc[j], 0, 0, 0);
        }
    }
    int quad = lane >> 4, colid = lane & 15;
#pragma unroll
    for (int j = 0; j < 2; ++j) {
        int col = (w * 2 + j) * 16 + colid;
        float bb = bm2[col];
#pragma unroll
        for (int r = 0; r < 4; ++r) {
            int row = rg * 16 + quad * 4 + r;
            float v = fmaxf(acc[j][r] + bb, 0.f);
            Hb[row * HD + col] = v;
            if (hout) hout[row * HD + col] = v;
        }
    }
}

// ---------------------------------------------------------------------------
extern "C" void kernel_launch(void* const* d_in, const int* in_sizes, int n_in,
                              void* d_out, int out_size, void* d_ws, size_t ws_size,
                              hipStream_t stream) {
    const float* obs_traj     = (const float*)d_in[0];
    const float* obs_traj_rel = (const float*)d_in[1];
    const float* h0    = (const float*)d_in[3];
    const float* c0    = (const float*)d_in[4];
    const float* W_emb = (const float*)d_in[6];
    const float* b_emb = (const float*)d_in[7];
    const float* W_ih  = (const float*)d_in[8];
    const float* b_ih  = (const float*)d_in[9];
    const float* W_hh  = (const float*)d_in[10];
    const float* b_hh  = (const float*)d_in[11];
    const float* W_pos = (const float*)d_in[12];
    const float* b_pos = (const float*)d_in[13];
    const float* Wp_emb= (const float*)d_in[14];
    const float* bp_emb= (const float*)d_in[15];
    const float* Wp1   = (const float*)d_in[16];
    const float* bp1   = (const float*)d_in[17];
    const float* Wp2   = (const float*)d_in[18];
    const float* bp2   = (const float*)d_in[19];
    const float* Wm1   = (const float*)d_in[20];
    const float* bm1   = (const float*)d_in[21];
    const float* Wm2   = (const float*)d_in[22];
    const float* bm2   = (const float*)d_in[23];

    float* ws = (float*)d_ws;
    float* Hb    = ws; ws += B * HD;
    float* Cb    = ws; ws += B * HD;
    float* POSb  = ws; ws += B * 2;
    float* DIN   = ws; ws += B * ED;
    float* AbF   = ws; ws += B * MIDD;   // frag-order u (96 scenes x 16kt x 64 x 8)
    float* M0    = ws; ws += MIDD;
    float* M1    = ws; ws += MIDD;
    float* CV    = ws; ws += MIDD;
    float* M0F   = ws; ws += 16 * 64 * 8;
    float* M1F   = ws; ws += 16 * 64 * 8;
    unsigned short* us = (unsigned short*)ws;
    unsigned short* Hbf    = us; us += B * HD;
    unsigned short* POOLbf = us; us += B * BOT;
    unsigned short* Y1Mbf  = us; us += B * MLPH;
    unsigned short* WcatF  = us; us += 6 * 32 * 64 * 8;
    unsigned short* Wp1F2  = us; us += 5 * 32 * 64 * 8;
    unsigned short* Wp2F   = us; us += MIDD * BOT;
    unsigned short* Wm1F   = us; us += CTXD * MLPH;
    unsigned short* Wm2F   = us; us += MLPH * HD;

    float* out = (float*)d_out;
    float* rels_out = out;                 // (12,1536,2)
    float* h_out    = out + SEQL * B * 2;  // (1536,128)

    // setup
    {
        int tot = 16 * 64 * 64;   // Wp2: K=512, NT=64
        swizzleB_kernel<<<(tot + 255) / 256, 256, 0, stream>>>(Wp2, Wp2F, 64, MIDD, tot);
        tot = 36 * 64 * 64;       // Wm1: K=1152, NT=64
        swizzleB_kernel<<<(tot + 255) / 256, 256, 0, stream>>>(Wm1, Wm1F, 64, CTXD, tot);
        tot = 32 * 8 * 64;        // Wm2: K=1024, NT=8
        swizzleB_kernel<<<(tot + 255) / 256, 256, 0, stream>>>(Wm2, Wm2F, 8, MLPH, tot);
        swizzle_cat_kernel<<<(6 * 32 * 64 + 255) / 256, 256, 0, stream>>>(W_ih, W_hh, WcatF);
    }
    mcvec_kernel<<<2, 256, 0, stream>>>(Wp1, Wp_emb, bp_emb, bp1, M0, M1, CV);
    swizzle_p1_kernel<<<(5 * 32 * 64 + 255) / 256, 256, 0, stream>>>(Wp1, CV, Wp1F2);
    m01f_kernel<<<32, 256, 0, stream>>>(M0, M1, M0F, M1F);
    init_kernel<<<B, 128, 0, stream>>>(obs_traj, obs_traj_rel, h0, c0, W_emb, b_emb,
                                       Hb, Cb, POSb, DIN);

    for (int s = 0; s < SEQL; ++s) {
        step_kernel<<<G, 512, 0, stream>>>(
            WcatF, b_ih, b_hh, W_pos, b_pos, W_emb, b_emb, Wp1F2,
            Hb, Cb, POSb, DIN, Hbf, AbF, rels_out + s * B * 2);
        pool_gemm10_kernel<<<G * 8, 256, 0, stream>>>(AbF, POSb, M0F, M1F, Wp2F, bp2, POOLbf);
        mlp1_mfma_kernel<<<dim3(24, 16), 256, 0, stream>>>(Hbf, POOLbf, Wm1F, bm1, Y1Mbf);
        mlp2_mfma_kernel<<<G, 256, 0, stream>>>(Y1Mbf, Wm2F, bm2, Hb,
                                                (s == SEQL - 1) ? h_out : (float*)nullptr);
    }
}

// Round 12
// 1104.855 us; speedup vs baseline: 1.2094x; 1.2094x over previous
//
#include <hip/hip_runtime.h>
#include <math.h>

#define OBS 8
#define SEQL 12
#define G 96
#define PP 16
#define B 1536
#define HD 128
#define ED 64
#define BOT 1024
#define MIDD 512
#define CTXD (HD + BOT)   /* 1152 */
#define MLPH 1024

typedef __attribute__((ext_vector_type(8))) short bf16x8;
typedef __attribute__((ext_vector_type(4))) float f32x4;

__device__ inline short f2bf(float x) {
    union { float f; unsigned u; } v; v.f = x;
    unsigned r = v.u + 0x7fffu + ((v.u >> 16) & 1u);   // RNE
    return (short)(r >> 16);
}

// ---------------------------------------------------------------------------
// setup kernels
// ---------------------------------------------------------------------------
// B-matrix -> MFMA-fragment-order bf16. src is (Nrows x Kcols) row-major fp32.
// dst unit u = (kt*NT + nt)*64 + lane: B[n=nt*16+(l&15)][k=kt*32+((l>>4)<<3)+e]
__global__ void swizzleB_kernel(const float* __restrict__ src, unsigned short* __restrict__ dst,
                                int NT, int K, int total) {
    int u = blockIdx.x * 256 + threadIdx.x;
    if (u >= total) return;
    int l = u & 63; int v = u >> 6; int nt = v % NT; int kt = v / NT;
    int n = nt * 16 + (l & 15);
    int k = kt * 32 + ((l >> 4) << 3);
    const float* s = src + n * K + k;
    float4 s0 = *(const float4*)s;
    float4 s1 = *(const float4*)(s + 4);
    bf16x8 o;
    o[0] = f2bf(s0.x); o[1] = f2bf(s0.y); o[2] = f2bf(s0.z); o[3] = f2bf(s0.w);
    o[4] = f2bf(s1.x); o[5] = f2bf(s1.y); o[6] = f2bf(s1.z); o[7] = f2bf(s1.w);
    *(bf16x8*)(dst + u * 8) = o;
}

// gates B = [W_ih | W_hh] (512 x 192) -> frag order (6 kt x 32 nt)
__global__ void swizzle_cat_kernel(const float* __restrict__ W_ih, const float* __restrict__ W_hh,
                                   unsigned short* __restrict__ dst) {
    int u = blockIdx.x * 256 + threadIdx.x;   // 6*32*64 = 12288 units
    if (u >= 6 * 32 * 64) return;
    int l = u & 63; int v = u >> 6; int nt = v & 31; int kt = v >> 5;
    int n = nt * 16 + (l & 15);
    int k0 = kt * 32 + ((l >> 4) << 3);
    bf16x8 o;
#pragma unroll
    for (int e = 0; e < 8; ++e) {
        int k = k0 + e;
        float val = (k < ED) ? W_ih[n * ED + k] : W_hh[n * HD + (k - ED)];
        o[e] = f2bf(val);
    }
    *(bf16x8*)(dst + u * 8) = o;
}

// u B-matrix = [Wp1_h | 0 | 0 | CV | 0pad] (512 x 160) -> frag order (5 kt x 32 nt)
__global__ void swizzle_p1_kernel(const float* __restrict__ Wp1,
                                  const float* __restrict__ CV,
                                  unsigned short* __restrict__ dst) {
    int u = blockIdx.x * 256 + threadIdx.x;   // 5*32*64 = 10240 units
    if (u >= 5 * 32 * 64) return;
    int l = u & 63; int v = u >> 6; int nt = v & 31; int kt = v >> 5;
    int n = nt * 16 + (l & 15);
    int k0 = kt * 32 + ((l >> 4) << 3);
    bf16x8 o;
#pragma unroll
    for (int e = 0; e < 8; ++e) {
        int k = k0 + e;
        float val;
        if (k < HD)           val = Wp1[n * (ED + HD) + ED + k];
        else if (k == HD + 2) val = CV[n];
        else                  val = 0.f;
        o[e] = f2bf(val);
    }
    *(bf16x8*)(dst + u * 8) = o;
}

// M = Wp1[:, :64] @ Wp_emb  (512x2), cvec = Wp1[:, :64] @ bp_emb + bp1
__global__ void mcvec_kernel(const float* __restrict__ Wp1, const float* __restrict__ Wp_emb,
                             const float* __restrict__ bp_emb, const float* __restrict__ bp1,
                             float* __restrict__ M0, float* __restrict__ M1, float* __restrict__ CV) {
    int r = blockIdx.x * blockDim.x + threadIdx.x;
    if (r >= MIDD) return;
    float m0 = 0.f, m1 = 0.f, cv = 0.f;
    for (int e = 0; e < ED; ++e) {
        float w = Wp1[r * (ED + HD) + e];
        m0 += w * Wp_emb[e * 2 + 0];
        m1 += w * Wp_emb[e * 2 + 1];
        cv += w * bp_emb[e];
    }
    M0[r] = m0; M1[r] = m1; CV[r] = cv + bp1[r];
}

// frag-order fp32 M tables: M0F[(kt*64+lane)*8+e] = M0[kt*32+(lane>>4)*8+e]
__global__ void m01f_kernel(const float* __restrict__ M0, const float* __restrict__ M1,
                            float* __restrict__ M0F, float* __restrict__ M1F) {
    int id = blockIdx.x * 256 + threadIdx.x;   // 16*64*8 = 8192
    if (id >= 16 * 64 * 8) return;
    int e = id & 7;
    int lane = (id >> 3) & 63;
    int kt = id >> 9;
    int k = kt * 32 + ((lane >> 4) << 3) + e;
    M0F[id] = M0[k];
    M1F[id] = M1[k];
}

__global__ void init_kernel(const float* __restrict__ obs_traj, const float* __restrict__ obs_traj_rel,
                            const float* __restrict__ h0, const float* __restrict__ c0,
                            const float* __restrict__ W_emb, const float* __restrict__ b_emb,
                            float* __restrict__ Hb, float* __restrict__ Cb,
                            float* __restrict__ POSb, float* __restrict__ DIN) {
    int b = blockIdx.x;
    int t = threadIdx.x; // 128
    Hb[b * HD + t] = h0[b * HD + t];
    Cb[b * HD + t] = c0[b * HD + t];
    if (t < 2) POSb[b * 2 + t] = obs_traj[((OBS - 1) * B + b) * 2 + t];
    if (t < ED) {
        float rx = obs_traj_rel[((OBS - 1) * B + b) * 2 + 0];
        float ry = obs_traj_rel[((OBS - 1) * B + b) * 2 + 1];
        DIN[b * ED + t] = W_emb[t * 2 + 0] * rx + W_emb[t * 2 + 1] * ry + b_emb[t];
    }
}

// ---------------------------------------------------------------------------
// fused step: gates MFMA -> LSTM cell (in-reg) -> rel_pos -> POS/DIN update ->
// u MFMA (u = Wp1h*h + CV, position-free). Block = one scene, 512 thr.
// Writes AbF (u) in MFMA A-fragment order (fp32).
// ---------------------------------------------------------------------------
__global__ __launch_bounds__(512) void step_kernel(
    const unsigned short* __restrict__ WcatF, const float* __restrict__ b_ih,
    const float* __restrict__ b_hh,
    const float* __restrict__ W_pos, const float* __restrict__ b_pos,
    const float* __restrict__ W_emb, const float* __restrict__ b_emb,
    const unsigned short* __restrict__ Wp1F2,
    float* __restrict__ Hb, float* __restrict__ Cb, float* __restrict__ POSb,
    float* __restrict__ DIN, unsigned short* __restrict__ Hbf,
    float* __restrict__ AbF, float* __restrict__ rel_out) {

    __shared__ unsigned short gf[6 * 64 * 8];    // gates A-frags, 6KB
    __shared__ unsigned short a2f[5 * 64 * 8];   // u A-frags, 5KB
    __shared__ float hsh[16 * HD];               // h_lstm, 8KB
    __shared__ float relsh[16][4];

    int gsc = blockIdx.x;          // scene
    int t = threadIdx.x;
    int lane = t & 63, w = t >> 6;
    int colid = lane & 15, quad = lane >> 4;

    // build gates A-frags: [din(64) | h_prev(128)], K=192 = 6 kt
    if (t < 384) {
        int kt = t >> 6;
        int j = lane & 15;
        int b = gsc * PP + j;
        int k0 = kt * 32 + ((lane >> 4) << 3);
        float4 x0, x1;
        if (k0 < ED) {
            const float4* p = (const float4*)(DIN + b * ED + k0);
            x0 = p[0]; x1 = p[1];
        } else {
            const float4* p = (const float4*)(Hb + b * HD + (k0 - ED));
            x0 = p[0]; x1 = p[1];
        }
        bf16x8 o;
        o[0] = f2bf(x0.x); o[1] = f2bf(x0.y); o[2] = f2bf(x0.z); o[3] = f2bf(x0.w);
        o[4] = f2bf(x1.x); o[5] = f2bf(x1.y); o[6] = f2bf(x1.z); o[7] = f2bf(x1.w);
        *(bf16x8*)(gf + t * 8) = o;
    }
    __syncthreads();

    // gates MFMA
    f32x4 acc[4];
#pragma unroll
    for (int gi = 0; gi < 4; ++gi) acc[gi] = (f32x4)0.f;
#pragma unroll
    for (int kt = 0; kt < 6; ++kt) {
        bf16x8 af = *(const bf16x8*)(gf + (kt * 64 + lane) * 8);
#pragma unroll
        for (int gi = 0; gi < 4; ++gi) {
            bf16x8 bfr = *(const bf16x8*)(WcatF + ((kt * 32 + gi * 8 + w) * 64 + lane) * 8);
            acc[gi] = __builtin_amdgcn_mfma_f32_16x16x32_bf16(af, bfr, acc[gi], 0, 0, 0);
        }
    }
    // LSTM cell, all four gates in-wave
    int hcol = w * 16 + colid;
    float bias[4];
#pragma unroll
    for (int gi = 0; gi < 4; ++gi) {
        int n = (gi * 8 + w) * 16 + colid;
        bias[gi] = b_ih[n] + b_hh[n];
    }
#pragma unroll
    for (int r = 0; r < 4; ++r) {
        int row = quad * 4 + r;
        int b = gsc * PP + row;
        float gI = acc[0][r] + bias[0];
        float gF = acc[1][r] + bias[1];
        float gG = acc[2][r] + bias[2];
        float gO = acc[3][r] + bias[3];
        float c = Cb[b * HD + hcol];
        float cn = (1.f / (1.f + expf(-gF))) * c + (1.f / (1.f + expf(-gI))) * tanhf(gG);
        float hn = (1.f / (1.f + expf(-gO))) * tanhf(cn);
        Cb[b * HD + hcol] = cn;
        Hbf[b * HD + hcol] = (unsigned short)f2bf(hn);
        hsh[row * HD + hcol] = hn;
    }
    __syncthreads();

    // rel_pos: 32 threads per row, shuffle reduce
    {
        int row = t >> 5, kk = t & 31;
        float r0 = 0.f, r1 = 0.f;
#pragma unroll
        for (int q = 0; q < 4; ++q) {
            int k = kk + q * 32;
            float hv = hsh[row * HD + k];
            r0 = fmaf(hv, W_pos[k], r0);
            r1 = fmaf(hv, W_pos[HD + k], r1);
        }
#pragma unroll
        for (int m = 16; m >= 1; m >>= 1) {
            r0 += __shfl_xor(r0, m, 64);
            r1 += __shfl_xor(r1, m, 64);
        }
        if (kk == 0) {
            int b = gsc * PP + row;
            r0 += b_pos[0]; r1 += b_pos[1];
            float px = POSb[b * 2 + 0] + r0;
            float py = POSb[b * 2 + 1] + r1;
            POSb[b * 2 + 0] = px; POSb[b * 2 + 1] = py;
            rel_out[b * 2 + 0] = r0; rel_out[b * 2 + 1] = r1;
            relsh[row][0] = r0; relsh[row][1] = r1; relsh[row][2] = px; relsh[row][3] = py;
        }
    }
    __syncthreads();

    // next dec_in
#pragma unroll
    for (int rep = 0; rep < 2; ++rep) {
        int idx = rep * 512 + t;
        int row = idx >> 6, e = idx & 63;
        int b = gsc * PP + row;
        DIN[b * ED + e] = W_emb[e * 2 + 0] * relsh[row][0] +
                          W_emb[e * 2 + 1] * relsh[row][1] + b_emb[e];
    }
    // u A-frags: [h(128) | 0 | 0 | 1 | 0pad], K=160 = 5 kt
    if (t < 320) {
        int kt = t >> 6;
        int j = lane & 15;
        int k0 = kt * 32 + ((lane >> 4) << 3);
        bf16x8 o;
#pragma unroll
        for (int e = 0; e < 8; ++e) {
            int k = k0 + e;
            float v;
            if (k < HD)            v = hsh[j * HD + k];
            else if (k == HD + 2)  v = 1.f;
            else                   v = 0.f;
            o[e] = f2bf(v);
        }
        *(bf16x8*)(a2f + t * 8) = o;
    }
    __syncthreads();

    // u MFMA: wave w -> nt = w*4+q (512 cols total); write AbF in frag order
    f32x4 acc2[4];
#pragma unroll
    for (int q = 0; q < 4; ++q) acc2[q] = (f32x4)0.f;
#pragma unroll
    for (int kt = 0; kt < 5; ++kt) {
        bf16x8 af = *(const bf16x8*)(a2f + (kt * 64 + lane) * 8);
#pragma unroll
        for (int q = 0; q < 4; ++q) {
            bf16x8 bfr = *(const bf16x8*)(Wp1F2 + ((kt * 32 + w * 4 + q) * 64 + lane) * 8);
            acc2[q] = __builtin_amdgcn_mfma_f32_16x16x32_bf16(af, bfr, acc2[q], 0, 0, 0);
        }
    }
#pragma unroll
    for (int q = 0; q < 4; ++q)
#pragma unroll
        for (int r = 0; r < 4; ++r) {
            int j = quad * 4 + r;                 // row within scene
            int k = (w * 4 + q) * 16 + colid;     // col (k-dim of pool GEMM)
            int kt2 = k >> 5, lk = (k >> 3) & 3, e = k & 7;
            AbF[((gsc * 16 + kt2) * 64 + lk * 16 + j) * 8 + e] = acc2[q][r];
        }
}

// ---------------------------------------------------------------------------
// pool_gemm11 = gemm9 tiling (8 nt x 2 i per wave, (256,3), dbuf LDS streams)
// + R11's part-major conflict-free u/M staging (float4 @ 16B lane stride,
// same bank pattern as the B reads). Composition of the two validated halves.
// grid = 1536 (g, io, colq), 256 thr.
// ---------------------------------------------------------------------------
__global__ __launch_bounds__(256, 3) void pool_gemm11_kernel(
    const float* __restrict__ AbF, const float* __restrict__ POSb,
    const float* __restrict__ M0F, const float* __restrict__ M1F,
    const unsigned short* __restrict__ Wp2F, const float* __restrict__ bp2,
    unsigned short* __restrict__ POOLbf) {

    __shared__ __align__(16) unsigned short Bst[2][8 * 64 * 8];   // 2 x 8KB
    __shared__ __align__(16) float UMst[2][6][64 * 4];            // 2 x 6KB part-major

    int bi = blockIdx.x;
    int g = bi % 96;                 // scene -> XCD-local
    int rest = bi / 96;              // 0..15
    int io = rest >> 3;              // 0..1
    int colq = rest & 7;             // 0..7
    int t = threadIdx.x, lane = t & 63, w = t >> 6;
    int i0 = io * 8 + w * 2;
    int j = lane & 15;
    int ntb = colq * 8;

    float pjx = POSb[(g * PP + j) * 2 + 0];
    float pjy = POSb[(g * PP + j) * 2 + 1];
    float dx[2], dy[2];
#pragma unroll
    for (int p = 0; p < 2; ++p) {
        int gi = g * PP + i0 + p;
        dx[p] = pjx - POSb[gi * 2 + 0];
        dy[p] = pjy - POSb[gi * 2 + 1];
    }

    const float* ag = AbF + (size_t)g * (16 * 64 * 8);

    // stage streams for k-tile kt into buffer buf (all 256 threads)
    auto stage = [&](int kt, int buf) {
        // B: 8 nt x 64 lanes = 512 units, 2 per thread
#pragma unroll
        for (int r = 0; r < 2; ++r) {
            int u = r * 256 + t;            // 0..511
            int nt = u >> 6, l = u & 63;
            *(bf16x8*)&Bst[buf][u * 8] =
                *(const bf16x8*)(Wp2F + ((kt * 64 + ntb + nt) * 64 + l) * 8);
        }
        // u/M: 6 parts x 64 lanes, part-major float4 (16B lane stride)
        {
            int pt = t >> 6;                 // 0..3 (parts 0..3)
            int l = t & 63;
            const float* src = (pt < 2) ? (ag + kt * 512 + l * 8 + pt * 4)
                                        : (M0F + kt * 512 + l * 8 + (pt - 2) * 4);
            *(float4*)&UMst[buf][pt][l * 4] = *(const float4*)src;
            if (t < 128) {                   // parts 4..5 (M1F)
                int pt2 = 4 + (t >> 6);
                *(float4*)&UMst[buf][pt2][l * 4] =
                    *(const float4*)(M1F + kt * 512 + l * 8 + (t >> 6) * 4);
            }
        }
    };

    f32x4 acc[2][8];
#pragma unroll
    for (int p = 0; p < 2; ++p)
#pragma unroll
        for (int n = 0; n < 8; ++n) acc[p][n] = (f32x4)0.f;

    stage(0, 0);
    __syncthreads();

    for (int kt = 0; kt < 16; ++kt) {
        int buf = kt & 1;
        if (kt < 15) stage(kt + 1, buf ^ 1);

        float4 u0  = *(const float4*)&UMst[buf][0][lane * 4];
        float4 u1  = *(const float4*)&UMst[buf][1][lane * 4];
        float4 m00 = *(const float4*)&UMst[buf][2][lane * 4];
        float4 m01 = *(const float4*)&UMst[buf][3][lane * 4];
        float4 m10 = *(const float4*)&UMst[buf][4][lane * 4];
        float4 m11 = *(const float4*)&UMst[buf][5][lane * 4];

        bf16x8 af[2];
#pragma unroll
        for (int p = 0; p < 2; ++p) {
            float dxp = dx[p], dyp = dy[p];
            af[p][0] = f2bf(fmaxf(fmaf(m10.x, dyp, fmaf(m00.x, dxp, u0.x)), 0.f));
            af[p][1] = f2bf(fmaxf(fmaf(m10.y, dyp, fmaf(m00.y, dxp, u0.y)), 0.f));
            af[p][2] = f2bf(fmaxf(fmaf(m10.z, dyp, fmaf(m00.z, dxp, u0.z)), 0.f));
            af[p][3] = f2bf(fmaxf(fmaf(m10.w, dyp, fmaf(m00.w, dxp, u0.w)), 0.f));
            af[p][4] = f2bf(fmaxf(fmaf(m11.x, dyp, fmaf(m01.x, dxp, u1.x)), 0.f));
            af[p][5] = f2bf(fmaxf(fmaf(m11.y, dyp, fmaf(m01.y, dxp, u1.y)), 0.f));
            af[p][6] = f2bf(fmaxf(fmaf(m11.z, dyp, fmaf(m01.z, dxp, u1.z)), 0.f));
            af[p][7] = f2bf(fmaxf(fmaf(m11.w, dyp, fmaf(m01.w, dxp, u1.w)), 0.f));
        }
#pragma unroll
        for (int ng = 0; ng < 2; ++ng) {
            bf16x8 bfr[4];
#pragma unroll
            for (int n = 0; n < 4; ++n)
                bfr[n] = *(const bf16x8*)&Bst[buf][((ng * 4 + n) * 64 + lane) * 8];
#pragma unroll
            for (int n = 0; n < 4; ++n) {
                acc[0][ng * 4 + n] =
                    __builtin_amdgcn_mfma_f32_16x16x32_bf16(af[0], bfr[n], acc[0][ng * 4 + n], 0, 0, 0);
                acc[1][ng * 4 + n] =
                    __builtin_amdgcn_mfma_f32_16x16x32_bf16(af[1], bfr[n], acc[1][ng * 4 + n], 0, 0, 0);
            }
        }
        __syncthreads();   // staging of kt+1 done; reads of buf done
    }

    int quad = lane >> 4, colid = lane & 15;
#pragma unroll
    for (int p = 0; p < 2; ++p) {
        int i = g * PP + i0 + p;
#pragma unroll
        for (int n = 0; n < 8; ++n) {
            float m = fmaxf(fmaxf(acc[p][n][0], acc[p][n][1]),
                            fmaxf(acc[p][n][2], acc[p][n][3]));
            m = fmaxf(m, __shfl_xor(m, 16, 64));
            m = fmaxf(m, __shfl_xor(m, 32, 64));
            if (quad == 0) {
                int col = (ntb + n) * 16 + colid;
                float v = fmaxf(m + bp2[col], 0.f);
                POOLbf[i * BOT + col] = (unsigned short)f2bf(v);
            }
        }
    }
}

// ---------------------------------------------------------------------------
// MLP1 (MFMA): [Hbf | POOLbf] (1536x1152) @ Wm1F -> relu -> Y1Mbf (1536x1024)
// ---------------------------------------------------------------------------
__global__ __launch_bounds__(256) void mlp1_mfma_kernel(
    const unsigned short* __restrict__ Hbf, const unsigned short* __restrict__ POOLbf,
    const unsigned short* __restrict__ Wm1F, const float* __restrict__ bm1,
    unsigned short* __restrict__ Y1Mbf) {

    __shared__ unsigned short a_f[16 * 64 * 8];   // 16KB
    int mg = blockIdx.x;       // 0..23
    int ng = blockIdx.y;       // 0..15
    int t = threadIdx.x, lane = t & 63, w = t >> 6;
    int rh = w >> 1, nh = w & 1;

    f32x4 acc[2][2];
#pragma unroll
    for (int a = 0; a < 2; ++a)
#pragma unroll
        for (int b = 0; b < 2; ++b) acc[a][b] = (f32x4)0.f;

    for (int c = 0; c < 9; ++c) {
        __syncthreads();
#pragma unroll
        for (int u0 = 0; u0 < 1024; u0 += 256) {
            int u = u0 + t;
            int rg = u >> 8, kt = (u >> 6) & 3, l = u & 63;
            int row = mg * 64 + rg * 16 + (l & 15);
            int kl = kt * 32 + ((l >> 4) << 3);
            const unsigned short* src = (c == 0) ? (Hbf + row * HD + kl)
                                                 : (POOLbf + row * BOT + (c - 1) * 128 + kl);
            *(bf16x8*)(a_f + u * 8) = *(const bf16x8*)src;
        }
        __syncthreads();
#pragma unroll
        for (int kt = 0; kt < 4; ++kt) {
            int ktg = c * 4 + kt;
            bf16x8 bfr[2];
#pragma unroll
            for (int j = 0; j < 2; ++j) {
                int ntg = ng * 4 + nh * 2 + j;
                bfr[j] = *(const bf16x8*)(Wm1F + ((ktg * 64 + ntg) * 64 + lane) * 8);
            }
#pragma unroll
            for (int ri = 0; ri < 2; ++ri) {
                int rg = rh * 2 + ri;
                bf16x8 af = *(const bf16x8*)(a_f + ((rg * 4 + kt) * 64 + lane) * 8);
#pragma unroll
                for (int j = 0; j < 2; ++j)
                    acc[ri][j] = __builtin_amdgcn_mfma_f32_16x16x32_bf16(af, bfr[j], acc[ri][j], 0, 0, 0);
            }
        }
    }
    int quad = lane >> 4, colid = lane & 15;
#pragma unroll
    for (int ri = 0; ri < 2; ++ri)
#pragma unroll
        for (int j = 0; j < 2; ++j) {
            int col = ng * 64 + (nh * 2 + j) * 16 + colid;
            float bb = bm1[col];
#pragma unroll
            for (int r = 0; r < 4; ++r) {
                int row = mg * 64 + (rh * 2 + ri) * 16 + quad * 4 + r;
                float v = fmaxf(acc[ri][j][r] + bb, 0.f);
                Y1Mbf[row * MLPH + col] = (unsigned short)f2bf(v);
            }
        }
}

// ---------------------------------------------------------------------------
// MLP2 (MFMA): Y1Mbf (1536x1024) @ Wm2F -> relu -> Hb fp32 (and h_out last step)
// ---------------------------------------------------------------------------
__global__ __launch_bounds__(256) void mlp2_mfma_kernel(
    const unsigned short* __restrict__ Y1Mbf, const unsigned short* __restrict__ Wm2F,
    const float* __restrict__ bm2, float* __restrict__ Hb, float* __restrict__ hout) {

    __shared__ unsigned short a_f[32 * 64 * 8];   // 32KB
    int rg = blockIdx.x;   // 0..95
    int t = threadIdx.x, lane = t & 63, w = t >> 6;

#pragma unroll
    for (int u0 = 0; u0 < 2048; u0 += 256) {
        int u = u0 + t;
        int kt = u >> 6, l = u & 63;
        int row = rg * 16 + (l & 15);
        int kl = kt * 32 + ((l >> 4) << 3);
        *(bf16x8*)(a_f + u * 8) = *(const bf16x8*)(Y1Mbf + row * MLPH + kl);
    }
    __syncthreads();

    f32x4 acc[2];
    acc[0] = (f32x4)0.f; acc[1] = (f32x4)0.f;
    for (int kt = 0; kt < 32; ++kt) {
        bf16x8 af = *(const bf16x8*)(a_f + (kt * 64 + lane) * 8);
#pragma unroll
        for (int j = 0; j < 2; ++j) {
            int ntg = w * 2 + j;
            bf16x8 bfr = *(const bf16x8*)(Wm2F + ((kt * 8 + ntg) * 64 + lane) * 8);
            acc[j] = __builtin_amdgcn_mfma_f32_16x16x32_bf16(af, bfr, acc[j], 0, 0, 0);
        }
    }
    int quad = lane >> 4, colid = lane & 15;
#pragma unroll
    for (int j = 0; j < 2; ++j) {
        int col = (w * 2 + j) * 16 + colid;
        float bb = bm2[col];
#pragma unroll
        for (int r = 0; r < 4; ++r) {
            int row = rg * 16 + quad * 4 + r;
            float v = fmaxf(acc[j][r] + bb, 0.f);
            Hb[row * HD + col] = v;
            if (hout) hout[row * HD + col] = v;
        }
    }
}

// ---------------------------------------------------------------------------
extern "C" void kernel_launch(void* const* d_in, const int* in_sizes, int n_in,
                              void* d_out, int out_size, void* d_ws, size_t ws_size,
                              hipStream_t stream) {
    const float* obs_traj     = (const float*)d_in[0];
    const float* obs_traj_rel = (const float*)d_in[1];
    const float* h0    = (const float*)d_in[3];
    const float* c0    = (const float*)d_in[4];
    const float* W_emb = (const float*)d_in[6];
    const float* b_emb = (const float*)d_in[7];
    const float* W_ih  = (const float*)d_in[8];
    const float* b_ih  = (const float*)d_in[9];
    const float* W_hh  = (const float*)d_in[10];
    const float* b_hh  = (const float*)d_in[11];
    const float* W_pos = (const float*)d_in[12];
    const float* b_pos = (const float*)d_in[13];
    const float* Wp_emb= (const float*)d_in[14];
    const float* bp_emb= (const float*)d_in[15];
    const float* Wp1   = (const float*)d_in[16];
    const float* bp1   = (const float*)d_in[17];
    const float* Wp2   = (const float*)d_in[18];
    const float* bp2   = (const float*)d_in[19];
    const float* Wm1   = (const float*)d_in[20];
    const float* bm1   = (const float*)d_in[21];
    const float* Wm2   = (const float*)d_in[22];
    const float* bm2   = (const float*)d_in[23];

    float* ws = (float*)d_ws;
    float* Hb    = ws; ws += B * HD;
    float* Cb    = ws; ws += B * HD;
    float* POSb  = ws; ws += B * 2;
    float* DIN   = ws; ws += B * ED;
    float* AbF   = ws; ws += B * MIDD;   // frag-order u (96 scenes x 16kt x 64 x 8)
    float* M0    = ws; ws += MIDD;
    float* M1    = ws; ws += MIDD;
    float* CV    = ws; ws += MIDD;
    float* M0F   = ws; ws += 16 * 64 * 8;
    float* M1F   = ws; ws += 16 * 64 * 8;
    unsigned short* us = (unsigned short*)ws;
    unsigned short* Hbf    = us; us += B * HD;
    unsigned short* POOLbf = us; us += B * BOT;
    unsigned short* Y1Mbf  = us; us += B * MLPH;
    unsigned short* WcatF  = us; us += 6 * 32 * 64 * 8;
    unsigned short* Wp1F2  = us; us += 5 * 32 * 64 * 8;
    unsigned short* Wp2F   = us; us += MIDD * BOT;
    unsigned short* Wm1F   = us; us += CTXD * MLPH;
    unsigned short* Wm2F   = us; us += MLPH * HD;

    float* out = (float*)d_out;
    float* rels_out = out;                 // (12,1536,2)
    float* h_out    = out + SEQL * B * 2;  // (1536,128)

    // setup
    {
        int tot = 16 * 64 * 64;   // Wp2: K=512, NT=64
        swizzleB_kernel<<<(tot + 255) / 256, 256, 0, stream>>>(Wp2, Wp2F, 64, MIDD, tot);
        tot = 36 * 64 * 64;       // Wm1: K=1152, NT=64
        swizzleB_kernel<<<(tot + 255) / 256, 256, 0, stream>>>(Wm1, Wm1F, 64, CTXD, tot);
        tot = 32 * 8 * 64;        // Wm2: K=1024, NT=8
        swizzleB_kernel<<<(tot + 255) / 256, 256, 0, stream>>>(Wm2, Wm2F, 8, MLPH, tot);
        swizzle_cat_kernel<<<(6 * 32 * 64 + 255) / 256, 256, 0, stream>>>(W_ih, W_hh, WcatF);
    }
    mcvec_kernel<<<2, 256, 0, stream>>>(Wp1, Wp_emb, bp_emb, bp1, M0, M1, CV);
    swizzle_p1_kernel<<<(5 * 32 * 64 + 255) / 256, 256, 0, stream>>>(Wp1, CV, Wp1F2);
    m01f_kernel<<<32, 256, 0, stream>>>(M0, M1, M0F, M1F);
    init_kernel<<<B, 128, 0, stream>>>(obs_traj, obs_traj_rel, h0, c0, W_emb, b_emb,
                                       Hb, Cb, POSb, DIN);

    for (int s = 0; s < SEQL; ++s) {
        step_kernel<<<G, 512, 0, stream>>>(
            WcatF, b_ih, b_hh, W_pos, b_pos, W_emb, b_emb, Wp1F2,
            Hb, Cb, POSb, DIN, Hbf, AbF, rels_out + s * B * 2);
        pool_gemm11_kernel<<<G * 16, 256, 0, stream>>>(AbF, POSb, M0F, M1F, Wp2F, bp2, POOLbf);
        mlp1_mfma_kernel<<<dim3(24, 16), 256, 0, stream>>>(Hbf, POOLbf, Wm1F, bm1, Y1Mbf);
        mlp2_mfma_kernel<<<G, 256, 0, stream>>>(Y1Mbf, Wm2F, bm2, Hb,
                                                (s == SEQL - 1) ? h_out : (float*)nullptr);
    }
}

// Round 13
// 1095.813 us; speedup vs baseline: 1.2194x; 1.0083x over previous
//
#include <hip/hip_runtime.h>
#include <hip/hip_bf16.h>
#include <math.h>

#define OBS 8
#define SEQL 12
#define G 96
#define PP 16
#define B 1536
#define HD 128
#define ED 64
#define BOT 1024
#define MIDD 512
#define CTXD (HD + BOT)   /* 1152 */
#define MLPH 1024

typedef __attribute__((ext_vector_type(8))) short bf16x8;
typedef __attribute__((ext_vector_type(4))) float f32x4;

__device__ inline short f2bf(float x) {
    union { float f; unsigned u; } v; v.f = x;
    unsigned r = v.u + 0x7fffu + ((v.u >> 16) & 1u);   // RNE
    return (short)(r >> 16);
}

// HW packed fp32x2 -> bf16x2 (v_cvt_pk_bf16_f32, RNE). a -> low 16 bits.
__device__ inline unsigned pk2bf(float a, float b) {
    union { __hip_bfloat162 h; unsigned u; } c;
    c.h = __float22bfloat162_rn(float2{a, b});
    return c.u;
}

// ---------------------------------------------------------------------------
// setup kernels
// ---------------------------------------------------------------------------
// B-matrix -> MFMA-fragment-order bf16. src is (Nrows x Kcols) row-major fp32.
// dst unit u = (kt*NT + nt)*64 + lane: B[n=nt*16+(l&15)][k=kt*32+((l>>4)<<3)+e]
__global__ void swizzleB_kernel(const float* __restrict__ src, unsigned short* __restrict__ dst,
                                int NT, int K, int total) {
    int u = blockIdx.x * 256 + threadIdx.x;
    if (u >= total) return;
    int l = u & 63; int v = u >> 6; int nt = v % NT; int kt = v / NT;
    int n = nt * 16 + (l & 15);
    int k = kt * 32 + ((l >> 4) << 3);
    const float* s = src + n * K + k;
    float4 s0 = *(const float4*)s;
    float4 s1 = *(const float4*)(s + 4);
    bf16x8 o;
    o[0] = f2bf(s0.x); o[1] = f2bf(s0.y); o[2] = f2bf(s0.z); o[3] = f2bf(s0.w);
    o[4] = f2bf(s1.x); o[5] = f2bf(s1.y); o[6] = f2bf(s1.z); o[7] = f2bf(s1.w);
    *(bf16x8*)(dst + u * 8) = o;
}

// gates B = [W_ih | W_hh] (512 x 192) -> frag order (6 kt x 32 nt)
__global__ void swizzle_cat_kernel(const float* __restrict__ W_ih, const float* __restrict__ W_hh,
                                   unsigned short* __restrict__ dst) {
    int u = blockIdx.x * 256 + threadIdx.x;   // 6*32*64 = 12288 units
    if (u >= 6 * 32 * 64) return;
    int l = u & 63; int v = u >> 6; int nt = v & 31; int kt = v >> 5;
    int n = nt * 16 + (l & 15);
    int k0 = kt * 32 + ((l >> 4) << 3);
    bf16x8 o;
#pragma unroll
    for (int e = 0; e < 8; ++e) {
        int k = k0 + e;
        float val = (k < ED) ? W_ih[n * ED + k] : W_hh[n * HD + (k - ED)];
        o[e] = f2bf(val);
    }
    *(bf16x8*)(dst + u * 8) = o;
}

// u B-matrix = [Wp1_h | 0 | 0 | CV | 0pad] (512 x 160) -> frag order (5 kt x 32 nt)
__global__ void swizzle_p1_kernel(const float* __restrict__ Wp1,
                                  const float* __restrict__ CV,
                                  unsigned short* __restrict__ dst) {
    int u = blockIdx.x * 256 + threadIdx.x;   // 5*32*64 = 10240 units
    if (u >= 5 * 32 * 64) return;
    int l = u & 63; int v = u >> 6; int nt = v & 31; int kt = v >> 5;
    int n = nt * 16 + (l & 15);
    int k0 = kt * 32 + ((l >> 4) << 3);
    bf16x8 o;
#pragma unroll
    for (int e = 0; e < 8; ++e) {
        int k = k0 + e;
        float val;
        if (k < HD)           val = Wp1[n * (ED + HD) + ED + k];
        else if (k == HD + 2) val = CV[n];
        else                  val = 0.f;
        o[e] = f2bf(val);
    }
    *(bf16x8*)(dst + u * 8) = o;
}

// M = Wp1[:, :64] @ Wp_emb  (512x2), cvec = Wp1[:, :64] @ bp_emb + bp1
__global__ void mcvec_kernel(const float* __restrict__ Wp1, const float* __restrict__ Wp_emb,
                             const float* __restrict__ bp_emb, const float* __restrict__ bp1,
                             float* __restrict__ M0, float* __restrict__ M1, float* __restrict__ CV) {
    int r = blockIdx.x * blockDim.x + threadIdx.x;
    if (r >= MIDD) return;
    float m0 = 0.f, m1 = 0.f, cv = 0.f;
    for (int e = 0; e < ED; ++e) {
        float w = Wp1[r * (ED + HD) + e];
        m0 += w * Wp_emb[e * 2 + 0];
        m1 += w * Wp_emb[e * 2 + 1];
        cv += w * bp_emb[e];
    }
    M0[r] = m0; M1[r] = m1; CV[r] = cv + bp1[r];
}

// frag-order fp32 M tables: M0F[(kt*64+lane)*8+e] = M0[kt*32+(lane>>4)*8+e]
__global__ void m01f_kernel(const float* __restrict__ M0, const float* __restrict__ M1,
                            float* __restrict__ M0F, float* __restrict__ M1F) {
    int id = blockIdx.x * 256 + threadIdx.x;   // 16*64*8 = 8192
    if (id >= 16 * 64 * 8) return;
    int e = id & 7;
    int lane = (id >> 3) & 63;
    int kt = id >> 9;
    int k = kt * 32 + ((lane >> 4) << 3) + e;
    M0F[id] = M0[k];
    M1F[id] = M1[k];
}

__global__ void init_kernel(const float* __restrict__ obs_traj, const float* __restrict__ obs_traj_rel,
                            const float* __restrict__ h0, const float* __restrict__ c0,
                            const float* __restrict__ W_emb, const float* __restrict__ b_emb,
                            float* __restrict__ Hb, float* __restrict__ Cb,
                            float* __restrict__ POSb, float* __restrict__ DIN) {
    int b = blockIdx.x;
    int t = threadIdx.x; // 128
    Hb[b * HD + t] = h0[b * HD + t];
    Cb[b * HD + t] = c0[b * HD + t];
    if (t < 2) POSb[b * 2 + t] = obs_traj[((OBS - 1) * B + b) * 2 + t];
    if (t < ED) {
        float rx = obs_traj_rel[((OBS - 1) * B + b) * 2 + 0];
        float ry = obs_traj_rel[((OBS - 1) * B + b) * 2 + 1];
        DIN[b * ED + t] = W_emb[t * 2 + 0] * rx + W_emb[t * 2 + 1] * ry + b_emb[t];
    }
}

// ---------------------------------------------------------------------------
// fused step: gates MFMA -> LSTM cell (in-reg) -> rel_pos -> POS/DIN update ->
// u MFMA (u = Wp1h*h + CV, position-free). Block = one scene, 512 thr.
// Writes AbF (u) in MFMA A-fragment order (fp32).
// ---------------------------------------------------------------------------
__global__ __launch_bounds__(512) void step_kernel(
    const unsigned short* __restrict__ WcatF, const float* __restrict__ b_ih,
    const float* __restrict__ b_hh,
    const float* __restrict__ W_pos, const float* __restrict__ b_pos,
    const float* __restrict__ W_emb, const float* __restrict__ b_emb,
    const unsigned short* __restrict__ Wp1F2,
    float* __restrict__ Hb, float* __restrict__ Cb, float* __restrict__ POSb,
    float* __restrict__ DIN, unsigned short* __restrict__ Hbf,
    float* __restrict__ AbF, float* __restrict__ rel_out) {

    __shared__ unsigned short gf[6 * 64 * 8];    // gates A-frags, 6KB
    __shared__ unsigned short a2f[5 * 64 * 8];   // u A-frags, 5KB
    __shared__ float hsh[16 * HD];               // h_lstm, 8KB
    __shared__ float relsh[16][4];

    int gsc = blockIdx.x;          // scene
    int t = threadIdx.x;
    int lane = t & 63, w = t >> 6;
    int colid = lane & 15, quad = lane >> 4;

    // build gates A-frags: [din(64) | h_prev(128)], K=192 = 6 kt
    if (t < 384) {
        int kt = t >> 6;
        int j = lane & 15;
        int b = gsc * PP + j;
        int k0 = kt * 32 + ((lane >> 4) << 3);
        float4 x0, x1;
        if (k0 < ED) {
            const float4* p = (const float4*)(DIN + b * ED + k0);
            x0 = p[0]; x1 = p[1];
        } else {
            const float4* p = (const float4*)(Hb + b * HD + (k0 - ED));
            x0 = p[0]; x1 = p[1];
        }
        union { bf16x8 v; unsigned u32[4]; } o;
        o.u32[0] = pk2bf(x0.x, x0.y);
        o.u32[1] = pk2bf(x0.z, x0.w);
        o.u32[2] = pk2bf(x1.x, x1.y);
        o.u32[3] = pk2bf(x1.z, x1.w);
        *(bf16x8*)(gf + t * 8) = o.v;
    }
    __syncthreads();

    // gates MFMA
    f32x4 acc[4];
#pragma unroll
    for (int gi = 0; gi < 4; ++gi) acc[gi] = (f32x4)0.f;
#pragma unroll
    for (int kt = 0; kt < 6; ++kt) {
        bf16x8 af = *(const bf16x8*)(gf + (kt * 64 + lane) * 8);
#pragma unroll
        for (int gi = 0; gi < 4; ++gi) {
            bf16x8 bfr = *(const bf16x8*)(WcatF + ((kt * 32 + gi * 8 + w) * 64 + lane) * 8);
            acc[gi] = __builtin_amdgcn_mfma_f32_16x16x32_bf16(af, bfr, acc[gi], 0, 0, 0);
        }
    }
    // LSTM cell, all four gates in-wave
    int hcol = w * 16 + colid;
    float bias[4];
#pragma unroll
    for (int gi = 0; gi < 4; ++gi) {
        int n = (gi * 8 + w) * 16 + colid;
        bias[gi] = b_ih[n] + b_hh[n];
    }
#pragma unroll
    for (int r = 0; r < 4; ++r) {
        int row = quad * 4 + r;
        int b = gsc * PP + row;
        float gI = acc[0][r] + bias[0];
        float gF = acc[1][r] + bias[1];
        float gG = acc[2][r] + bias[2];
        float gO = acc[3][r] + bias[3];
        float c = Cb[b * HD + hcol];
        float cn = (1.f / (1.f + expf(-gF))) * c + (1.f / (1.f + expf(-gI))) * tanhf(gG);
        float hn = (1.f / (1.f + expf(-gO))) * tanhf(cn);
        Cb[b * HD + hcol] = cn;
        Hbf[b * HD + hcol] = (unsigned short)f2bf(hn);
        hsh[row * HD + hcol] = hn;
    }
    __syncthreads();

    // rel_pos: 32 threads per row, shuffle reduce
    {
        int row = t >> 5, kk = t & 31;
        float r0 = 0.f, r1 = 0.f;
#pragma unroll
        for (int q = 0; q < 4; ++q) {
            int k = kk + q * 32;
            float hv = hsh[row * HD + k];
            r0 = fmaf(hv, W_pos[k], r0);
            r1 = fmaf(hv, W_pos[HD + k], r1);
        }
#pragma unroll
        for (int m = 16; m >= 1; m >>= 1) {
            r0 += __shfl_xor(r0, m, 64);
            r1 += __shfl_xor(r1, m, 64);
        }
        if (kk == 0) {
            int b = gsc * PP + row;
            r0 += b_pos[0]; r1 += b_pos[1];
            float px = POSb[b * 2 + 0] + r0;
            float py = POSb[b * 2 + 1] + r1;
            POSb[b * 2 + 0] = px; POSb[b * 2 + 1] = py;
            rel_out[b * 2 + 0] = r0; rel_out[b * 2 + 1] = r1;
            relsh[row][0] = r0; relsh[row][1] = r1; relsh[row][2] = px; relsh[row][3] = py;
        }
    }
    __syncthreads();

    // next dec_in
#pragma unroll
    for (int rep = 0; rep < 2; ++rep) {
        int idx = rep * 512 + t;
        int row = idx >> 6, e = idx & 63;
        int b = gsc * PP + row;
        DIN[b * ED + e] = W_emb[e * 2 + 0] * relsh[row][0] +
                          W_emb[e * 2 + 1] * relsh[row][1] + b_emb[e];
    }
    // u A-frags: [h(128) | 0 | 0 | 1 | 0pad], K=160 = 5 kt
    if (t < 320) {
        int kt = t >> 6;
        int j = lane & 15;
        int k0 = kt * 32 + ((lane >> 4) << 3);
        float e8[8];
#pragma unroll
        for (int e = 0; e < 8; ++e) {
            int k = k0 + e;
            float v;
            if (k < HD)            v = hsh[j * HD + k];
            else if (k == HD + 2)  v = 1.f;
            else                   v = 0.f;
            e8[e] = v;
        }
        union { bf16x8 v; unsigned u32[4]; } o;
        o.u32[0] = pk2bf(e8[0], e8[1]);
        o.u32[1] = pk2bf(e8[2], e8[3]);
        o.u32[2] = pk2bf(e8[4], e8[5]);
        o.u32[3] = pk2bf(e8[6], e8[7]);
        *(bf16x8*)(a2f + t * 8) = o.v;
    }
    __syncthreads();

    // u MFMA: wave w -> nt = w*4+q (512 cols total); write AbF in frag order
    f32x4 acc2[4];
#pragma unroll
    for (int q = 0; q < 4; ++q) acc2[q] = (f32x4)0.f;
#pragma unroll
    for (int kt = 0; kt < 5; ++kt) {
        bf16x8 af = *(const bf16x8*)(a2f + (kt * 64 + lane) * 8);
#pragma unroll
        for (int q = 0; q < 4; ++q) {
            bf16x8 bfr = *(const bf16x8*)(Wp1F2 + ((kt * 32 + w * 4 + q) * 64 + lane) * 8);
            acc2[q] = __builtin_amdgcn_mfma_f32_16x16x32_bf16(af, bfr, acc2[q], 0, 0, 0);
        }
    }
#pragma unroll
    for (int q = 0; q < 4; ++q)
#pragma unroll
        for (int r = 0; r < 4; ++r) {
            int j = quad * 4 + r;                 // row within scene
            int k = (w * 4 + q) * 16 + colid;     // col (k-dim of pool GEMM)
            int kt2 = k >> 5, lk = (k >> 3) & 3, e = k & 7;
            AbF[((gsc * 16 + kt2) * 64 + lk * 16 + j) * 8 + e] = acc2[q][r];
        }
}

// ---------------------------------------------------------------------------
// pool_gemm12 = gemm11 (gemm9 tiling + conflict-free part-major u/M staging)
// with the A-build's bf16 pack done by HW v_cvt_pk_bf16_f32 (pk2bf) —
// cuts the dominant build-VALU from ~8 to ~4.5 inst/element.
// grid = 1536 (g, io, colq), 256 thr, (256,3).
// ---------------------------------------------------------------------------
__global__ __launch_bounds__(256, 3) void pool_gemm12_kernel(
    const float* __restrict__ AbF, const float* __restrict__ POSb,
    const float* __restrict__ M0F, const float* __restrict__ M1F,
    const unsigned short* __restrict__ Wp2F, const float* __restrict__ bp2,
    unsigned short* __restrict__ POOLbf) {

    __shared__ __align__(16) unsigned short Bst[2][8 * 64 * 8];   // 2 x 8KB
    __shared__ __align__(16) float UMst[2][6][64 * 4];            // 2 x 6KB part-major

    int bi = blockIdx.x;
    int g = bi % 96;                 // scene -> XCD-local
    int rest = bi / 96;              // 0..15
    int io = rest >> 3;              // 0..1
    int colq = rest & 7;             // 0..7
    int t = threadIdx.x, lane = t & 63, w = t >> 6;
    int i0 = io * 8 + w * 2;
    int j = lane & 15;
    int ntb = colq * 8;

    float pjx = POSb[(g * PP + j) * 2 + 0];
    float pjy = POSb[(g * PP + j) * 2 + 1];
    float dx[2], dy[2];
#pragma unroll
    for (int p = 0; p < 2; ++p) {
        int gi = g * PP + i0 + p;
        dx[p] = pjx - POSb[gi * 2 + 0];
        dy[p] = pjy - POSb[gi * 2 + 1];
    }

    const float* ag = AbF + (size_t)g * (16 * 64 * 8);

    // stage streams for k-tile kt into buffer buf (all 256 threads)
    auto stage = [&](int kt, int buf) {
        // B: 8 nt x 64 lanes = 512 units, 2 per thread
#pragma unroll
        for (int r = 0; r < 2; ++r) {
            int u = r * 256 + t;            // 0..511
            int nt = u >> 6, l = u & 63;
            *(bf16x8*)&Bst[buf][u * 8] =
                *(const bf16x8*)(Wp2F + ((kt * 64 + ntb + nt) * 64 + l) * 8);
        }
        // u/M: 6 parts x 64 lanes, part-major float4 (16B lane stride)
        {
            int pt = t >> 6;                 // 0..3 (parts 0..3)
            int l = t & 63;
            const float* src = (pt < 2) ? (ag + kt * 512 + l * 8 + pt * 4)
                                        : (M0F + kt * 512 + l * 8 + (pt - 2) * 4);
            *(float4*)&UMst[buf][pt][l * 4] = *(const float4*)src;
            if (t < 128) {                   // parts 4..5 (M1F)
                int pt2 = 4 + (t >> 6);
                *(float4*)&UMst[buf][pt2][l * 4] =
                    *(const float4*)(M1F + kt * 512 + l * 8 + (t >> 6) * 4);
            }
        }
    };

    f32x4 acc[2][8];
#pragma unroll
    for (int p = 0; p < 2; ++p)
#pragma unroll
        for (int n = 0; n < 8; ++n) acc[p][n] = (f32x4)0.f;

    stage(0, 0);
    __syncthreads();

    for (int kt = 0; kt < 16; ++kt) {
        int buf = kt & 1;
        if (kt < 15) stage(kt + 1, buf ^ 1);

        float4 u0  = *(const float4*)&UMst[buf][0][lane * 4];
        float4 u1  = *(const float4*)&UMst[buf][1][lane * 4];
        float4 m00 = *(const float4*)&UMst[buf][2][lane * 4];
        float4 m01 = *(const float4*)&UMst[buf][3][lane * 4];
        float4 m10 = *(const float4*)&UMst[buf][4][lane * 4];
        float4 m11 = *(const float4*)&UMst[buf][5][lane * 4];

        bf16x8 af[2];
#pragma unroll
        for (int p = 0; p < 2; ++p) {
            float dxp = dx[p], dyp = dy[p];
            float r0 = fmaxf(fmaf(m10.x, dyp, fmaf(m00.x, dxp, u0.x)), 0.f);
            float r1 = fmaxf(fmaf(m10.y, dyp, fmaf(m00.y, dxp, u0.y)), 0.f);
            float r2 = fmaxf(fmaf(m10.z, dyp, fmaf(m00.z, dxp, u0.z)), 0.f);
            float r3 = fmaxf(fmaf(m10.w, dyp, fmaf(m00.w, dxp, u0.w)), 0.f);
            float r4 = fmaxf(fmaf(m11.x, dyp, fmaf(m01.x, dxp, u1.x)), 0.f);
            float r5 = fmaxf(fmaf(m11.y, dyp, fmaf(m01.y, dxp, u1.y)), 0.f);
            float r6 = fmaxf(fmaf(m11.z, dyp, fmaf(m01.z, dxp, u1.z)), 0.f);
            float r7 = fmaxf(fmaf(m11.w, dyp, fmaf(m01.w, dxp, u1.w)), 0.f);
            union { bf16x8 v; unsigned u32[4]; } o;
            o.u32[0] = pk2bf(r0, r1);
            o.u32[1] = pk2bf(r2, r3);
            o.u32[2] = pk2bf(r4, r5);
            o.u32[3] = pk2bf(r6, r7);
            af[p] = o.v;
        }
#pragma unroll
        for (int ng = 0; ng < 2; ++ng) {
            bf16x8 bfr[4];
#pragma unroll
            for (int n = 0; n < 4; ++n)
                bfr[n] = *(const bf16x8*)&Bst[buf][((ng * 4 + n) * 64 + lane) * 8];
#pragma unroll
            for (int n = 0; n < 4; ++n) {
                acc[0][ng * 4 + n] =
                    __builtin_amdgcn_mfma_f32_16x16x32_bf16(af[0], bfr[n], acc[0][ng * 4 + n], 0, 0, 0);
                acc[1][ng * 4 + n] =
                    __builtin_amdgcn_mfma_f32_16x16x32_bf16(af[1], bfr[n], acc[1][ng * 4 + n], 0, 0, 0);
            }
        }
        __syncthreads();   // staging of kt+1 done; reads of buf done
    }

    int quad = lane >> 4, colid = lane & 15;
#pragma unroll
    for (int p = 0; p < 2; ++p) {
        int i = g * PP + i0 + p;
#pragma unroll
        for (int n = 0; n < 8; ++n) {
            float m = fmaxf(fmaxf(acc[p][n][0], acc[p][n][1]),
                            fmaxf(acc[p][n][2], acc[p][n][3]));
            m = fmaxf(m, __shfl_xor(m, 16, 64));
            m = fmaxf(m, __shfl_xor(m, 32, 64));
            if (quad == 0) {
                int col = (ntb + n) * 16 + colid;
                float v = fmaxf(m + bp2[col], 0.f);
                POOLbf[i * BOT + col] = (unsigned short)f2bf(v);
            }
        }
    }
}

// ---------------------------------------------------------------------------
// MLP1 (MFMA): [Hbf | POOLbf] (1536x1152) @ Wm1F -> relu -> Y1Mbf (1536x1024)
// ---------------------------------------------------------------------------
__global__ __launch_bounds__(256) void mlp1_mfma_kernel(
    const unsigned short* __restrict__ Hbf, const unsigned short* __restrict__ POOLbf,
    const unsigned short* __restrict__ Wm1F, const float* __restrict__ bm1,
    unsigned short* __restrict__ Y1Mbf) {

    __shared__ unsigned short a_f[16 * 64 * 8];   // 16KB
    int mg = blockIdx.x;       // 0..23
    int ng = blockIdx.y;       // 0..15
    int t = threadIdx.x, lane = t & 63, w = t >> 6;
    int rh = w >> 1, nh = w & 1;

    f32x4 acc[2][2];
#pragma unroll
    for (int a = 0; a < 2; ++a)
#pragma unroll
        for (int b = 0; b < 2; ++b) acc[a][b] = (f32x4)0.f;

    for (int c = 0; c < 9; ++c) {
        __syncthreads();
#pragma unroll
        for (int u0 = 0; u0 < 1024; u0 += 256) {
            int u = u0 + t;
            int rg = u >> 8, kt = (u >> 6) & 3, l = u & 63;
            int row = mg * 64 + rg * 16 + (l & 15);
            int kl = kt * 32 + ((l >> 4) << 3);
            const unsigned short* src = (c == 0) ? (Hbf + row * HD + kl)
                                                 : (POOLbf + row * BOT + (c - 1) * 128 + kl);
            *(bf16x8*)(a_f + u * 8) = *(const bf16x8*)src;
        }
        __syncthreads();
#pragma unroll
        for (int kt = 0; kt < 4; ++kt) {
            int ktg = c * 4 + kt;
            bf16x8 bfr[2];
#pragma unroll
            for (int j = 0; j < 2; ++j) {
                int ntg = ng * 4 + nh * 2 + j;
                bfr[j] = *(const bf16x8*)(Wm1F + ((ktg * 64 + ntg) * 64 + lane) * 8);
            }
#pragma unroll
            for (int ri = 0; ri < 2; ++ri) {
                int rg = rh * 2 + ri;
                bf16x8 af = *(const bf16x8*)(a_f + ((rg * 4 + kt) * 64 + lane) * 8);
#pragma unroll
                for (int j = 0; j < 2; ++j)
                    acc[ri][j] = __builtin_amdgcn_mfma_f32_16x16x32_bf16(af, bfr[j], acc[ri][j], 0, 0, 0);
            }
        }
    }
    int quad = lane >> 4, colid = lane & 15;
#pragma unroll
    for (int ri = 0; ri < 2; ++ri)
#pragma unroll
        for (int j = 0; j < 2; ++j) {
            int col = ng * 64 + (nh * 2 + j) * 16 + colid;
            float bb = bm1[col];
#pragma unroll
            for (int r = 0; r < 4; ++r) {
                int row = mg * 64 + (rh * 2 + ri) * 16 + quad * 4 + r;
                float v = fmaxf(acc[ri][j][r] + bb, 0.f);
                Y1Mbf[row * MLPH + col] = (unsigned short)f2bf(v);
            }
        }
}

// ---------------------------------------------------------------------------
// MLP2 (MFMA): Y1Mbf (1536x1024) @ Wm2F -> relu -> Hb fp32 (and h_out last step)
// ---------------------------------------------------------------------------
__global__ __launch_bounds__(256) void mlp2_mfma_kernel(
    const unsigned short* __restrict__ Y1Mbf, const unsigned short* __restrict__ Wm2F,
    const float* __restrict__ bm2, float* __restrict__ Hb, float* __restrict__ hout) {

    __shared__ unsigned short a_f[32 * 64 * 8];   // 32KB
    int rg = blockIdx.x;   // 0..95
    int t = threadIdx.x, lane = t & 63, w = t >> 6;

#pragma unroll
    for (int u0 = 0; u0 < 2048; u0 += 256) {
        int u = u0 + t;
        int kt = u >> 6, l = u & 63;
        int row = rg * 16 + (l & 15);
        int kl = kt * 32 + ((l >> 4) << 3);
        *(bf16x8*)(a_f + u * 8) = *(const bf16x8*)(Y1Mbf + row * MLPH + kl);
    }
    __syncthreads();

    f32x4 acc[2];
    acc[0] = (f32x4)0.f; acc[1] = (f32x4)0.f;
    for (int kt = 0; kt < 32; ++kt) {
        bf16x8 af = *(const bf16x8*)(a_f + (kt * 64 + lane) * 8);
#pragma unroll
        for (int j = 0; j < 2; ++j) {
            int ntg = w * 2 + j;
            bf16x8 bfr = *(const bf16x8*)(Wm2F + ((kt * 8 + ntg) * 64 + lane) * 8);
            acc[j] = __builtin_amdgcn_mfma_f32_16x16x32_bf16(af, bfr, acc[j], 0, 0, 0);
        }
    }
    int quad = lane >> 4, colid = lane & 15;
#pragma unroll
    for (int j = 0; j < 2; ++j) {
        int col = (w * 2 + j) * 16 + colid;
        float bb = bm2[col];
#pragma unroll
        for (int r = 0; r < 4; ++r) {
            int row = rg * 16 + quad * 4 + r;
            float v = fmaxf(acc[j][r] + bb, 0.f);
            Hb[row * HD + col] = v;
            if (hout) hout[row * HD + col] = v;
        }
    }
}

// ---------------------------------------------------------------------------
extern "C" void kernel_launch(void* const* d_in, const int* in_sizes, int n_in,
                              void* d_out, int out_size, void* d_ws, size_t ws_size,
                              hipStream_t stream) {
    const float* obs_traj     = (const float*)d_in[0];
    const float* obs_traj_rel = (const float*)d_in[1];
    const float* h0    = (const float*)d_in[3];
    const float* c0    = (const float*)d_in[4];
    const float* W_emb = (const float*)d_in[6];
    const float* b_emb = (const float*)d_in[7];
    const float* W_ih  = (const float*)d_in[8];
    const float* b_ih  = (const float*)d_in[9];
    const float* W_hh  = (const float*)d_in[10];
    const float* b_hh  = (const float*)d_in[11];
    const float* W_pos = (const float*)d_in[12];
    const float* b_pos = (const float*)d_in[13];
    const float* Wp_emb= (const float*)d_in[14];
    const float* bp_emb= (const float*)d_in[15];
    const float* Wp1   = (const float*)d_in[16];
    const float* bp1   = (const float*)d_in[17];
    const float* Wp2   = (const float*)d_in[18];
    const float* bp2   = (const float*)d_in[19];
    const float* Wm1   = (const float*)d_in[20];
    const float* bm1   = (const float*)d_in[21];
    const float* Wm2   = (const float*)d_in[22];
    const float* bm2   = (const float*)d_in[23];

    float* ws = (float*)d_ws;
    float* Hb    = ws; ws += B * HD;
    float* Cb    = ws; ws += B * HD;
    float* POSb  = ws; ws += B * 2;
    float* DIN   = ws; ws += B * ED;
    float* AbF   = ws; ws += B * MIDD;   // frag-order u (96 scenes x 16kt x 64 x 8)
    float* M0    = ws; ws += MIDD;
    float* M1    = ws; ws += MIDD;
    float* CV    = ws; ws += MIDD;
    float* M0F   = ws; ws += 16 * 64 * 8;
    float* M1F   = ws; ws += 16 * 64 * 8;
    unsigned short* us = (unsigned short*)ws;
    unsigned short* Hbf    = us; us += B * HD;
    unsigned short* POOLbf = us; us += B * BOT;
    unsigned short* Y1Mbf  = us; us += B * MLPH;
    unsigned short* WcatF  = us; us += 6 * 32 * 64 * 8;
    unsigned short* Wp1F2  = us; us += 5 * 32 * 64 * 8;
    unsigned short* Wp2F   = us; us += MIDD * BOT;
    unsigned short* Wm1F   = us; us += CTXD * MLPH;
    unsigned short* Wm2F   = us; us += MLPH * HD;

    float* out = (float*)d_out;
    float* rels_out = out;                 // (12,1536,2)
    float* h_out    = out + SEQL * B * 2;  // (1536,128)

    // setup
    {
        int tot = 16 * 64 * 64;   // Wp2: K=512, NT=64
        swizzleB_kernel<<<(tot + 255) / 256, 256, 0, stream>>>(Wp2, Wp2F, 64, MIDD, tot);
        tot = 36 * 64 * 64;       // Wm1: K=1152, NT=64
        swizzleB_kernel<<<(tot + 255) / 256, 256, 0, stream>>>(Wm1, Wm1F, 64, CTXD, tot);
        tot = 32 * 8 * 64;        // Wm2: K=1024, NT=8
        swizzleB_kernel<<<(tot + 255) / 256, 256, 0, stream>>>(Wm2, Wm2F, 8, MLPH, tot);
        swizzle_cat_kernel<<<(6 * 32 * 64 + 255) / 256, 256, 0, stream>>>(W_ih, W_hh, WcatF);
    }
    mcvec_kernel<<<2, 256, 0, stream>>>(Wp1, Wp_emb, bp_emb, bp1, M0, M1, CV);
    swizzle_p1_kernel<<<(5 * 32 * 64 + 255) / 256, 256, 0, stream>>>(Wp1, CV, Wp1F2);
    m01f_kernel<<<32, 256, 0, stream>>>(M0, M1, M0F, M1F);
    init_kernel<<<B, 128, 0, stream>>>(obs_traj, obs_traj_rel, h0, c0, W_emb, b_emb,
                                       Hb, Cb, POSb, DIN);

    for (int s = 0; s < SEQL; ++s) {
        step_kernel<<<G, 512, 0, stream>>>(
            WcatF, b_ih, b_hh, W_pos, b_pos, W_emb, b_emb, Wp1F2,
            Hb, Cb, POSb, DIN, Hbf, AbF, rels_out + s * B * 2);
        pool_gemm12_kernel<<<G * 16, 256, 0, stream>>>(AbF, POSb, M0F, M1F, Wp2F, bp2, POOLbf);
        mlp1_mfma_kernel<<<dim3(24, 16), 256, 0, stream>>>(Hbf, POOLbf, Wm1F, bm1, Y1Mbf);
        mlp2_mfma_kernel<<<G, 256, 0, stream>>>(Y1Mbf, Wm2F, bm2, Hb,
                                                (s == SEQL - 1) ? h_out : (float*)nullptr);
    }
}

// Round 14
// 1094.446 us; speedup vs baseline: 1.2209x; 1.0012x over previous
//
#include <hip/hip_runtime.h>
#include <hip/hip_bf16.h>
#include <math.h>

#define OBS 8
#define SEQL 12
#define G 96
#define PP 16
#define B 1536
#define HD 128
#define ED 64
#define BOT 1024
#define MIDD 512
#define CTXD (HD + BOT)   /* 1152 */
#define MLPH 1024

typedef __attribute__((ext_vector_type(8))) short bf16x8;
typedef __attribute__((ext_vector_type(4))) float f32x4;

__device__ inline short f2bf(float x) {
    union { float f; unsigned u; } v; v.f = x;
    unsigned r = v.u + 0x7fffu + ((v.u >> 16) & 1u);   // RNE
    return (short)(r >> 16);
}

// HW packed fp32x2 -> bf16x2 (v_cvt_pk_bf16_f32, RNE). a -> low 16 bits.
__device__ inline unsigned pk2bf(float a, float b) {
    union { __hip_bfloat162 h; unsigned u; } c;
    c.h = __float22bfloat162_rn(float2{a, b});
    return c.u;
}

// ---------------------------------------------------------------------------
// setup kernels
// ---------------------------------------------------------------------------
// B-matrix -> MFMA-fragment-order bf16. src is (Nrows x Kcols) row-major fp32.
// dst unit u = (kt*NT + nt)*64 + lane: B[n=nt*16+(l&15)][k=kt*32+((l>>4)<<3)+e]
__global__ void swizzleB_kernel(const float* __restrict__ src, unsigned short* __restrict__ dst,
                                int NT, int K, int total) {
    int u = blockIdx.x * 256 + threadIdx.x;
    if (u >= total) return;
    int l = u & 63; int v = u >> 6; int nt = v % NT; int kt = v / NT;
    int n = nt * 16 + (l & 15);
    int k = kt * 32 + ((l >> 4) << 3);
    const float* s = src + n * K + k;
    float4 s0 = *(const float4*)s;
    float4 s1 = *(const float4*)(s + 4);
    bf16x8 o;
    o[0] = f2bf(s0.x); o[1] = f2bf(s0.y); o[2] = f2bf(s0.z); o[3] = f2bf(s0.w);
    o[4] = f2bf(s1.x); o[5] = f2bf(s1.y); o[6] = f2bf(s1.z); o[7] = f2bf(s1.w);
    *(bf16x8*)(dst + u * 8) = o;
}

// gates B = [W_ih | W_hh] (512 x 192) -> frag order (6 kt x 32 nt)
__global__ void swizzle_cat_kernel(const float* __restrict__ W_ih, const float* __restrict__ W_hh,
                                   unsigned short* __restrict__ dst) {
    int u = blockIdx.x * 256 + threadIdx.x;   // 6*32*64 = 12288 units
    if (u >= 6 * 32 * 64) return;
    int l = u & 63; int v = u >> 6; int nt = v & 31; int kt = v >> 5;
    int n = nt * 16 + (l & 15);
    int k0 = kt * 32 + ((l >> 4) << 3);
    bf16x8 o;
#pragma unroll
    for (int e = 0; e < 8; ++e) {
        int k = k0 + e;
        float val = (k < ED) ? W_ih[n * ED + k] : W_hh[n * HD + (k - ED)];
        o[e] = f2bf(val);
    }
    *(bf16x8*)(dst + u * 8) = o;
}

// u B-matrix = [Wp1_h | 0 | 0 | CV | 0pad] (512 x 160) -> frag order (5 kt x 32 nt)
__global__ void swizzle_p1_kernel(const float* __restrict__ Wp1,
                                  const float* __restrict__ CV,
                                  unsigned short* __restrict__ dst) {
    int u = blockIdx.x * 256 + threadIdx.x;   // 5*32*64 = 10240 units
    if (u >= 5 * 32 * 64) return;
    int l = u & 63; int v = u >> 6; int nt = v & 31; int kt = v >> 5;
    int n = nt * 16 + (l & 15);
    int k0 = kt * 32 + ((l >> 4) << 3);
    bf16x8 o;
#pragma unroll
    for (int e = 0; e < 8; ++e) {
        int k = k0 + e;
        float val;
        if (k < HD)           val = Wp1[n * (ED + HD) + ED + k];
        else if (k == HD + 2) val = CV[n];
        else                  val = 0.f;
        o[e] = f2bf(val);
    }
    *(bf16x8*)(dst + u * 8) = o;
}

// M = Wp1[:, :64] @ Wp_emb  (512x2), cvec = Wp1[:, :64] @ bp_emb + bp1
__global__ void mcvec_kernel(const float* __restrict__ Wp1, const float* __restrict__ Wp_emb,
                             const float* __restrict__ bp_emb, const float* __restrict__ bp1,
                             float* __restrict__ M0, float* __restrict__ M1, float* __restrict__ CV) {
    int r = blockIdx.x * blockDim.x + threadIdx.x;
    if (r >= MIDD) return;
    float m0 = 0.f, m1 = 0.f, cv = 0.f;
    for (int e = 0; e < ED; ++e) {
        float w = Wp1[r * (ED + HD) + e];
        m0 += w * Wp_emb[e * 2 + 0];
        m1 += w * Wp_emb[e * 2 + 1];
        cv += w * bp_emb[e];
    }
    M0[r] = m0; M1[r] = m1; CV[r] = cv + bp1[r];
}

// frag-order fp32 M tables: M0F[(kt*64+lane)*8+e] = M0[kt*32+(lane>>4)*8+e]
__global__ void m01f_kernel(const float* __restrict__ M0, const float* __restrict__ M1,
                            float* __restrict__ M0F, float* __restrict__ M1F) {
    int id = blockIdx.x * 256 + threadIdx.x;   // 16*64*8 = 8192
    if (id >= 16 * 64 * 8) return;
    int e = id & 7;
    int lane = (id >> 3) & 63;
    int kt = id >> 9;
    int k = kt * 32 + ((lane >> 4) << 3) + e;
    M0F[id] = M0[k];
    M1F[id] = M1[k];
}

__global__ void init_kernel(const float* __restrict__ obs_traj, const float* __restrict__ obs_traj_rel,
                            const float* __restrict__ h0, const float* __restrict__ c0,
                            const float* __restrict__ W_emb, const float* __restrict__ b_emb,
                            float* __restrict__ Hb, float* __restrict__ Cb,
                            float* __restrict__ POSb, float* __restrict__ DIN) {
    int b = blockIdx.x;
    int t = threadIdx.x; // 128
    Hb[b * HD + t] = h0[b * HD + t];
    Cb[b * HD + t] = c0[b * HD + t];
    if (t < 2) POSb[b * 2 + t] = obs_traj[((OBS - 1) * B + b) * 2 + t];
    if (t < ED) {
        float rx = obs_traj_rel[((OBS - 1) * B + b) * 2 + 0];
        float ry = obs_traj_rel[((OBS - 1) * B + b) * 2 + 1];
        DIN[b * ED + t] = W_emb[t * 2 + 0] * rx + W_emb[t * 2 + 1] * ry + b_emb[t];
    }
}

// ---------------------------------------------------------------------------
// fused step: gates MFMA -> LSTM cell (in-reg) -> rel_pos -> POS/DIN update ->
// u MFMA (u = Wp1h*h + CV, position-free). Block = one scene, 512 thr.
// Writes AbF (u) in MFMA A-fragment order (fp32).
// ---------------------------------------------------------------------------
__global__ __launch_bounds__(512) void step_kernel(
    const unsigned short* __restrict__ WcatF, const float* __restrict__ b_ih,
    const float* __restrict__ b_hh,
    const float* __restrict__ W_pos, const float* __restrict__ b_pos,
    const float* __restrict__ W_emb, const float* __restrict__ b_emb,
    const unsigned short* __restrict__ Wp1F2,
    float* __restrict__ Hb, float* __restrict__ Cb, float* __restrict__ POSb,
    float* __restrict__ DIN, unsigned short* __restrict__ Hbf,
    float* __restrict__ AbF, float* __restrict__ rel_out) {

    __shared__ unsigned short gf[6 * 64 * 8];    // gates A-frags, 6KB
    __shared__ unsigned short a2f[5 * 64 * 8];   // u A-frags, 5KB
    __shared__ float hsh[16 * HD];               // h_lstm, 8KB
    __shared__ float relsh[16][4];

    int gsc = blockIdx.x;          // scene
    int t = threadIdx.x;
    int lane = t & 63, w = t >> 6;
    int colid = lane & 15, quad = lane >> 4;

    // build gates A-frags: [din(64) | h_prev(128)], K=192 = 6 kt
    if (t < 384) {
        int kt = t >> 6;
        int j = lane & 15;
        int b = gsc * PP + j;
        int k0 = kt * 32 + ((lane >> 4) << 3);
        float4 x0, x1;
        if (k0 < ED) {
            const float4* p = (const float4*)(DIN + b * ED + k0);
            x0 = p[0]; x1 = p[1];
        } else {
            const float4* p = (const float4*)(Hb + b * HD + (k0 - ED));
            x0 = p[0]; x1 = p[1];
        }
        union { bf16x8 v; unsigned u32[4]; } o;
        o.u32[0] = pk2bf(x0.x, x0.y);
        o.u32[1] = pk2bf(x0.z, x0.w);
        o.u32[2] = pk2bf(x1.x, x1.y);
        o.u32[3] = pk2bf(x1.z, x1.w);
        *(bf16x8*)(gf + t * 8) = o.v;
    }
    __syncthreads();

    // gates MFMA
    f32x4 acc[4];
#pragma unroll
    for (int gi = 0; gi < 4; ++gi) acc[gi] = (f32x4)0.f;
#pragma unroll
    for (int kt = 0; kt < 6; ++kt) {
        bf16x8 af = *(const bf16x8*)(gf + (kt * 64 + lane) * 8);
#pragma unroll
        for (int gi = 0; gi < 4; ++gi) {
            bf16x8 bfr = *(const bf16x8*)(WcatF + ((kt * 32 + gi * 8 + w) * 64 + lane) * 8);
            acc[gi] = __builtin_amdgcn_mfma_f32_16x16x32_bf16(af, bfr, acc[gi], 0, 0, 0);
        }
    }
    // LSTM cell, all four gates in-wave
    int hcol = w * 16 + colid;
    float bias[4];
#pragma unroll
    for (int gi = 0; gi < 4; ++gi) {
        int n = (gi * 8 + w) * 16 + colid;
        bias[gi] = b_ih[n] + b_hh[n];
    }
#pragma unroll
    for (int r = 0; r < 4; ++r) {
        int row = quad * 4 + r;
        int b = gsc * PP + row;
        float gI = acc[0][r] + bias[0];
        float gF = acc[1][r] + bias[1];
        float gG = acc[2][r] + bias[2];
        float gO = acc[3][r] + bias[3];
        float c = Cb[b * HD + hcol];
        float cn = (1.f / (1.f + expf(-gF))) * c + (1.f / (1.f + expf(-gI))) * tanhf(gG);
        float hn = (1.f / (1.f + expf(-gO))) * tanhf(cn);
        Cb[b * HD + hcol] = cn;
        Hbf[b * HD + hcol] = (unsigned short)f2bf(hn);
        hsh[row * HD + hcol] = hn;
    }
    __syncthreads();

    // rel_pos: 32 threads per row, shuffle reduce
    {
        int row = t >> 5, kk = t & 31;
        float r0 = 0.f, r1 = 0.f;
#pragma unroll
        for (int q = 0; q < 4; ++q) {
            int k = kk + q * 32;
            float hv = hsh[row * HD + k];
            r0 = fmaf(hv, W_pos[k], r0);
            r1 = fmaf(hv, W_pos[HD + k], r1);
        }
#pragma unroll
        for (int m = 16; m >= 1; m >>= 1) {
            r0 += __shfl_xor(r0, m, 64);
            r1 += __shfl_xor(r1, m, 64);
        }
        if (kk == 0) {
            int b = gsc * PP + row;
            r0 += b_pos[0]; r1 += b_pos[1];
            float px = POSb[b * 2 + 0] + r0;
            float py = POSb[b * 2 + 1] + r1;
            POSb[b * 2 + 0] = px; POSb[b * 2 + 1] = py;
            rel_out[b * 2 + 0] = r0; rel_out[b * 2 + 1] = r1;
            relsh[row][0] = r0; relsh[row][1] = r1; relsh[row][2] = px; relsh[row][3] = py;
        }
    }
    __syncthreads();

    // next dec_in
#pragma unroll
    for (int rep = 0; rep < 2; ++rep) {
        int idx = rep * 512 + t;
        int row = idx >> 6, e = idx & 63;
        int b = gsc * PP + row;
        DIN[b * ED + e] = W_emb[e * 2 + 0] * relsh[row][0] +
                          W_emb[e * 2 + 1] * relsh[row][1] + b_emb[e];
    }
    // u A-frags: [h(128) | 0 | 0 | 1 | 0pad], K=160 = 5 kt
    if (t < 320) {
        int kt = t >> 6;
        int j = lane & 15;
        int k0 = kt * 32 + ((lane >> 4) << 3);
        float e8[8];
#pragma unroll
        for (int e = 0; e < 8; ++e) {
            int k = k0 + e;
            float v;
            if (k < HD)            v = hsh[j * HD + k];
            else if (k == HD + 2)  v = 1.f;
            else                   v = 0.f;
            e8[e] = v;
        }
        union { bf16x8 v; unsigned u32[4]; } o;
        o.u32[0] = pk2bf(e8[0], e8[1]);
        o.u32[1] = pk2bf(e8[2], e8[3]);
        o.u32[2] = pk2bf(e8[4], e8[5]);
        o.u32[3] = pk2bf(e8[6], e8[7]);
        *(bf16x8*)(a2f + t * 8) = o.v;
    }
    __syncthreads();

    // u MFMA: wave w -> nt = w*4+q (512 cols total); write AbF in frag order
    f32x4 acc2[4];
#pragma unroll
    for (int q = 0; q < 4; ++q) acc2[q] = (f32x4)0.f;
#pragma unroll
    for (int kt = 0; kt < 5; ++kt) {
        bf16x8 af = *(const bf16x8*)(a2f + (kt * 64 + lane) * 8);
#pragma unroll
        for (int q = 0; q < 4; ++q) {
            bf16x8 bfr = *(const bf16x8*)(Wp1F2 + ((kt * 32 + w * 4 + q) * 64 + lane) * 8);
            acc2[q] = __builtin_amdgcn_mfma_f32_16x16x32_bf16(af, bfr, acc2[q], 0, 0, 0);
        }
    }
#pragma unroll
    for (int q = 0; q < 4; ++q)
#pragma unroll
        for (int r = 0; r < 4; ++r) {
            int j = quad * 4 + r;                 // row within scene
            int k = (w * 4 + q) * 16 + colid;     // col (k-dim of pool GEMM)
            int kt2 = k >> 5, lk = (k >> 3) & 3, e = k & 7;
            AbF[((gsc * 16 + kt2) * 64 + lk * 16 + j) * 8 + e] = acc2[q][r];
        }
}

// ---------------------------------------------------------------------------
// pool_gemm13 = gemm12 with __launch_bounds__(256,4): measured footprint
// (56 arch + 64 acc = 120 regs, 28KB LDS) fits 4 blocks/CU -> 16 waves/CU,
// +33% latency-hiding for the per-kt staging round trip + barrier stalls
// that R10-R13 showed to be the binding constraint.
// grid = 1536 (g, io, colq), 256 thr.
// ---------------------------------------------------------------------------
__global__ __launch_bounds__(256, 4) void pool_gemm13_kernel(
    const float* __restrict__ AbF, const float* __restrict__ POSb,
    const float* __restrict__ M0F, const float* __restrict__ M1F,
    const unsigned short* __restrict__ Wp2F, const float* __restrict__ bp2,
    unsigned short* __restrict__ POOLbf) {

    __shared__ __align__(16) unsigned short Bst[2][8 * 64 * 8];   // 2 x 8KB
    __shared__ __align__(16) float UMst[2][6][64 * 4];            // 2 x 6KB part-major

    int bi = blockIdx.x;
    int g = bi % 96;                 // scene -> XCD-local
    int rest = bi / 96;              // 0..15
    int io = rest >> 3;              // 0..1
    int colq = rest & 7;             // 0..7
    int t = threadIdx.x, lane = t & 63, w = t >> 6;
    int i0 = io * 8 + w * 2;
    int j = lane & 15;
    int ntb = colq * 8;

    float pjx = POSb[(g * PP + j) * 2 + 0];
    float pjy = POSb[(g * PP + j) * 2 + 1];
    float dx[2], dy[2];
#pragma unroll
    for (int p = 0; p < 2; ++p) {
        int gi = g * PP + i0 + p;
        dx[p] = pjx - POSb[gi * 2 + 0];
        dy[p] = pjy - POSb[gi * 2 + 1];
    }

    const float* ag = AbF + (size_t)g * (16 * 64 * 8);

    // stage streams for k-tile kt into buffer buf (all 256 threads)
    auto stage = [&](int kt, int buf) {
        // B: 8 nt x 64 lanes = 512 units, 2 per thread
#pragma unroll
        for (int r = 0; r < 2; ++r) {
            int u = r * 256 + t;            // 0..511
            int nt = u >> 6, l = u & 63;
            *(bf16x8*)&Bst[buf][u * 8] =
                *(const bf16x8*)(Wp2F + ((kt * 64 + ntb + nt) * 64 + l) * 8);
        }
        // u/M: 6 parts x 64 lanes, part-major float4 (16B lane stride)
        {
            int pt = t >> 6;                 // 0..3 (parts 0..3)
            int l = t & 63;
            const float* src = (pt < 2) ? (ag + kt * 512 + l * 8 + pt * 4)
                                        : (M0F + kt * 512 + l * 8 + (pt - 2) * 4);
            *(float4*)&UMst[buf][pt][l * 4] = *(const float4*)src;
            if (t < 128) {                   // parts 4..5 (M1F)
                int pt2 = 4 + (t >> 6);
                *(float4*)&UMst[buf][pt2][l * 4] =
                    *(const float4*)(M1F + kt * 512 + l * 8 + (t >> 6) * 4);
            }
        }
    };

    f32x4 acc[2][8];
#pragma unroll
    for (int p = 0; p < 2; ++p)
#pragma unroll
        for (int n = 0; n < 8; ++n) acc[p][n] = (f32x4)0.f;

    stage(0, 0);
    __syncthreads();

    for (int kt = 0; kt < 16; ++kt) {
        int buf = kt & 1;
        if (kt < 15) stage(kt + 1, buf ^ 1);

        float4 u0  = *(const float4*)&UMst[buf][0][lane * 4];
        float4 u1  = *(const float4*)&UMst[buf][1][lane * 4];
        float4 m00 = *(const float4*)&UMst[buf][2][lane * 4];
        float4 m01 = *(const float4*)&UMst[buf][3][lane * 4];
        float4 m10 = *(const float4*)&UMst[buf][4][lane * 4];
        float4 m11 = *(const float4*)&UMst[buf][5][lane * 4];

        bf16x8 af[2];
#pragma unroll
        for (int p = 0; p < 2; ++p) {
            float dxp = dx[p], dyp = dy[p];
            float r0 = fmaxf(fmaf(m10.x, dyp, fmaf(m00.x, dxp, u0.x)), 0.f);
            float r1 = fmaxf(fmaf(m10.y, dyp, fmaf(m00.y, dxp, u0.y)), 0.f);
            float r2 = fmaxf(fmaf(m10.z, dyp, fmaf(m00.z, dxp, u0.z)), 0.f);
            float r3 = fmaxf(fmaf(m10.w, dyp, fmaf(m00.w, dxp, u0.w)), 0.f);
            float r4 = fmaxf(fmaf(m11.x, dyp, fmaf(m01.x, dxp, u1.x)), 0.f);
            float r5 = fmaxf(fmaf(m11.y, dyp, fmaf(m01.y, dxp, u1.y)), 0.f);
            float r6 = fmaxf(fmaf(m11.z, dyp, fmaf(m01.z, dxp, u1.z)), 0.f);
            float r7 = fmaxf(fmaf(m11.w, dyp, fmaf(m01.w, dxp, u1.w)), 0.f);
            union { bf16x8 v; unsigned u32[4]; } o;
            o.u32[0] = pk2bf(r0, r1);
            o.u32[1] = pk2bf(r2, r3);
            o.u32[2] = pk2bf(r4, r5);
            o.u32[3] = pk2bf(r6, r7);
            af[p] = o.v;
        }
#pragma unroll
        for (int ng = 0; ng < 2; ++ng) {
            bf16x8 bfr[4];
#pragma unroll
            for (int n = 0; n < 4; ++n)
                bfr[n] = *(const bf16x8*)&Bst[buf][((ng * 4 + n) * 64 + lane) * 8];
#pragma unroll
            for (int n = 0; n < 4; ++n) {
                acc[0][ng * 4 + n] =
                    __builtin_amdgcn_mfma_f32_16x16x32_bf16(af[0], bfr[n], acc[0][ng * 4 + n], 0, 0, 0);
                acc[1][ng * 4 + n] =
                    __builtin_amdgcn_mfma_f32_16x16x32_bf16(af[1], bfr[n], acc[1][ng * 4 + n], 0, 0, 0);
            }
        }
        __syncthreads();   // staging of kt+1 done; reads of buf done
    }

    int quad = lane >> 4, colid = lane & 15;
#pragma unroll
    for (int p = 0; p < 2; ++p) {
        int i = g * PP + i0 + p;
#pragma unroll
        for (int n = 0; n < 8; ++n) {
            float m = fmaxf(fmaxf(acc[p][n][0], acc[p][n][1]),
                            fmaxf(acc[p][n][2], acc[p][n][3]));
            m = fmaxf(m, __shfl_xor(m, 16, 64));
            m = fmaxf(m, __shfl_xor(m, 32, 64));
            if (quad == 0) {
                int col = (ntb + n) * 16 + colid;
                float v = fmaxf(m + bp2[col], 0.f);
                POOLbf[i * BOT + col] = (unsigned short)f2bf(v);
            }
        }
    }
}

// ---------------------------------------------------------------------------
// MLP1 (MFMA): [Hbf | POOLbf] (1536x1152) @ Wm1F -> relu -> Y1Mbf (1536x1024)
// ---------------------------------------------------------------------------
__global__ __launch_bounds__(256) void mlp1_mfma_kernel(
    const unsigned short* __restrict__ Hbf, const unsigned short* __restrict__ POOLbf,
    const unsigned short* __restrict__ Wm1F, const float* __restrict__ bm1,
    unsigned short* __restrict__ Y1Mbf) {

    __shared__ unsigned short a_f[16 * 64 * 8];   // 16KB
    int mg = blockIdx.x;       // 0..23
    int ng = blockIdx.y;       // 0..15
    int t = threadIdx.x, lane = t & 63, w = t >> 6;
    int rh = w >> 1, nh = w & 1;

    f32x4 acc[2][2];
#pragma unroll
    for (int a = 0; a < 2; ++a)
#pragma unroll
        for (int b = 0; b < 2; ++b) acc[a][b] = (f32x4)0.f;

    for (int c = 0; c < 9; ++c) {
        __syncthreads();
#pragma unroll
        for (int u0 = 0; u0 < 1024; u0 += 256) {
            int u = u0 + t;
            int rg = u >> 8, kt = (u >> 6) & 3, l = u & 63;
            int row = mg * 64 + rg * 16 + (l & 15);
            int kl = kt * 32 + ((l >> 4) << 3);
            const unsigned short* src = (c == 0) ? (Hbf + row * HD + kl)
                                                 : (POOLbf + row * BOT + (c - 1) * 128 + kl);
            *(bf16x8*)(a_f + u * 8) = *(const bf16x8*)src;
        }
        __syncthreads();
#pragma unroll
        for (int kt = 0; kt < 4; ++kt) {
            int ktg = c * 4 + kt;
            bf16x8 bfr[2];
#pragma unroll
            for (int j = 0; j < 2; ++j) {
                int ntg = ng * 4 + nh * 2 + j;
                bfr[j] = *(const bf16x8*)(Wm1F + ((ktg * 64 + ntg) * 64 + lane) * 8);
            }
#pragma unroll
            for (int ri = 0; ri < 2; ++ri) {
                int rg = rh * 2 + ri;
                bf16x8 af = *(const bf16x8*)(a_f + ((rg * 4 + kt) * 64 + lane) * 8);
#pragma unroll
                for (int j = 0; j < 2; ++j)
                    acc[ri][j] = __builtin_amdgcn_mfma_f32_16x16x32_bf16(af, bfr[j], acc[ri][j], 0, 0, 0);
            }
        }
    }
    int quad = lane >> 4, colid = lane & 15;
#pragma unroll
    for (int ri = 0; ri < 2; ++ri)
#pragma unroll
        for (int j = 0; j < 2; ++j) {
            int col = ng * 64 + (nh * 2 + j) * 16 + colid;
            float bb = bm1[col];
#pragma unroll
            for (int r = 0; r < 4; ++r) {
                int row = mg * 64 + (rh * 2 + ri) * 16 + quad * 4 + r;
                float v = fmaxf(acc[ri][j][r] + bb, 0.f);
                Y1Mbf[row * MLPH + col] = (unsigned short)f2bf(v);
            }
        }
}

// ---------------------------------------------------------------------------
// MLP2 (MFMA): Y1Mbf (1536x1024) @ Wm2F -> relu -> Hb fp32 (and h_out last step)
// ---------------------------------------------------------------------------
__global__ __launch_bounds__(256) void mlp2_mfma_kernel(
    const unsigned short* __restrict__ Y1Mbf, const unsigned short* __restrict__ Wm2F,
    const float* __restrict__ bm2, float* __restrict__ Hb, float* __restrict__ hout) {

    __shared__ unsigned short a_f[32 * 64 * 8];   // 32KB
    int rg = blockIdx.x;   // 0..95
    int t = threadIdx.x, lane = t & 63, w = t >> 6;

#pragma unroll
    for (int u0 = 0; u0 < 2048; u0 += 256) {
        int u = u0 + t;
        int kt = u >> 6, l = u & 63;
        int row = rg * 16 + (l & 15);
        int kl = kt * 32 + ((l >> 4) << 3);
        *(bf16x8*)(a_f + u * 8) = *(const bf16x8*)(Y1Mbf + row * MLPH + kl);
    }
    __syncthreads();

    f32x4 acc[2];
    acc[0] = (f32x4)0.f; acc[1] = (f32x4)0.f;
    for (int kt = 0; kt < 32; ++kt) {
        bf16x8 af = *(const bf16x8*)(a_f + (kt * 64 + lane) * 8);
#pragma unroll
        for (int j = 0; j < 2; ++j) {
            int ntg = w * 2 + j;
            bf16x8 bfr = *(const bf16x8*)(Wm2F + ((kt * 8 + ntg) * 64 + lane) * 8);
            acc[j] = __builtin_amdgcn_mfma_f32_16x16x32_bf16(af, bfr, acc[j], 0, 0, 0);
        }
    }
    int quad = lane >> 4, colid = lane & 15;
#pragma unroll
    for (int j = 0; j < 2; ++j) {
        int col = (w * 2 + j) * 16 + colid;
        float bb = bm2[col];
#pragma unroll
        for (int r = 0; r < 4; ++r) {
            int row = rg * 16 + quad * 4 + r;
            float v = fmaxf(acc[j][r] + bb, 0.f);
            Hb[row * HD + col] = v;
            if (hout) hout[row * HD + col] = v;
        }
    }
}

// ---------------------------------------------------------------------------
extern "C" void kernel_launch(void* const* d_in, const int* in_sizes, int n_in,
                              void* d_out, int out_size, void* d_ws, size_t ws_size,
                              hipStream_t stream) {
    const float* obs_traj     = (const float*)d_in[0];
    const float* obs_traj_rel = (const float*)d_in[1];
    const float* h0    = (const float*)d_in[3];
    const float* c0    = (const float*)d_in[4];
    const float* W_emb = (const float*)d_in[6];
    const float* b_emb = (const float*)d_in[7];
    const float* W_ih  = (const float*)d_in[8];
    const float* b_ih  = (const float*)d_in[9];
    const float* W_hh  = (const float*)d_in[10];
    const float* b_hh  = (const float*)d_in[11];
    const float* W_pos = (const float*)d_in[12];
    const float* b_pos = (const float*)d_in[13];
    const float* Wp_emb= (const float*)d_in[14];
    const float* bp_emb= (const float*)d_in[15];
    const float* Wp1   = (const float*)d_in[16];
    const float* bp1   = (const float*)d_in[17];
    const float* Wp2   = (const float*)d_in[18];
    const float* bp2   = (const float*)d_in[19];
    const float* Wm1   = (const float*)d_in[20];
    const float* bm1   = (const float*)d_in[21];
    const float* Wm2   = (const float*)d_in[22];
    const float* bm2   = (const float*)d_in[23];

    float* ws = (float*)d_ws;
    float* Hb    = ws; ws += B * HD;
    float* Cb    = ws; ws += B * HD;
    float* POSb  = ws; ws += B * 2;
    float* DIN   = ws; ws += B * ED;
    float* AbF   = ws; ws += B * MIDD;   // frag-order u (96 scenes x 16kt x 64 x 8)
    float* M0    = ws; ws += MIDD;
    float* M1    = ws; ws += MIDD;
    float* CV    = ws; ws += MIDD;
    float* M0F   = ws; ws += 16 * 64 * 8;
    float* M1F   = ws; ws += 16 * 64 * 8;
    unsigned short* us = (unsigned short*)ws;
    unsigned short* Hbf    = us; us += B * HD;
    unsigned short* POOLbf = us; us += B * BOT;
    unsigned short* Y1Mbf  = us; us += B * MLPH;
    unsigned short* WcatF  = us; us += 6 * 32 * 64 * 8;
    unsigned short* Wp1F2  = us; us += 5 * 32 * 64 * 8;
    unsigned short* Wp2F   = us; us += MIDD * BOT;
    unsigned short* Wm1F   = us; us += CTXD * MLPH;
    unsigned short* Wm2F   = us; us += MLPH * HD;

    float* out = (float*)d_out;
    float* rels_out = out;                 // (12,1536,2)
    float* h_out    = out + SEQL * B * 2;  // (1536,128)

    // setup
    {
        int tot = 16 * 64 * 64;   // Wp2: K=512, NT=64
        swizzleB_kernel<<<(tot + 255) / 256, 256, 0, stream>>>(Wp2, Wp2F, 64, MIDD, tot);
        tot = 36 * 64 * 64;       // Wm1: K=1152, NT=64
        swizzleB_kernel<<<(tot + 255) / 256, 256, 0, stream>>>(Wm1, Wm1F, 64, CTXD, tot);
        tot = 32 * 8 * 64;        // Wm2: K=1024, NT=8
        swizzleB_kernel<<<(tot + 255) / 256, 256, 0, stream>>>(Wm2, Wm2F, 8, MLPH, tot);
        swizzle_cat_kernel<<<(6 * 32 * 64 + 255) / 256, 256, 0, stream>>>(W_ih, W_hh, WcatF);
    }
    mcvec_kernel<<<2, 256, 0, stream>>>(Wp1, Wp_emb, bp_emb, bp1, M0, M1, CV);
    swizzle_p1_kernel<<<(5 * 32 * 64 + 255) / 256, 256, 0, stream>>>(Wp1, CV, Wp1F2);
    m01f_kernel<<<32, 256, 0, stream>>>(M0, M1, M0F, M1F);
    init_kernel<<<B, 128, 0, stream>>>(obs_traj, obs_traj_rel, h0, c0, W_emb, b_emb,
                                       Hb, Cb, POSb, DIN);

    for (int s = 0; s < SEQL; ++s) {
        step_kernel<<<G, 512, 0, stream>>>(
            WcatF, b_ih, b_hh, W_pos, b_pos, W_emb, b_emb, Wp1F2,
            Hb, Cb, POSb, DIN, Hbf, AbF, rels_out + s * B * 2);
        pool_gemm13_kernel<<<G * 16, 256, 0, stream>>>(AbF, POSb, M0F, M1F, Wp2F, bp2, POOLbf);
        mlp1_mfma_kernel<<<dim3(24, 16), 256, 0, stream>>>(Hbf, POOLbf, Wm1F, bm1, Y1Mbf);
        mlp2_mfma_kernel<<<G, 256, 0, stream>>>(Y1Mbf, Wm2F, bm2, Hb,
                                                (s == SEQL - 1) ? h_out : (float*)nullptr);
    }
}

// Round 15
// 1060.199 us; speedup vs baseline: 1.2604x; 1.0323x over previous
//
#include <hip/hip_runtime.h>
#include <hip/hip_bf16.h>
#include <math.h>

#define OBS 8
#define SEQL 12
#define G 96
#define PP 16
#define B 1536
#define HD 128
#define ED 64
#define BOT 1024
#define MIDD 512
#define CTXD (HD + BOT)   /* 1152 */
#define MLPH 1024

typedef __attribute__((ext_vector_type(8))) short bf16x8;
typedef __attribute__((ext_vector_type(4))) float f32x4;

__device__ inline short f2bf(float x) {
    union { float f; unsigned u; } v; v.f = x;
    unsigned r = v.u + 0x7fffu + ((v.u >> 16) & 1u);   // RNE
    return (short)(r >> 16);
}

// HW packed fp32x2 -> bf16x2 (v_cvt_pk_bf16_f32, RNE). a -> low 16 bits.
__device__ inline unsigned pk2bf(float a, float b) {
    union { __hip_bfloat162 h; unsigned u; } c;
    c.h = __float22bfloat162_rn(float2{a, b});
    return c.u;
}

// ---------------------------------------------------------------------------
// setup kernels
// ---------------------------------------------------------------------------
__global__ void swizzleB_kernel(const float* __restrict__ src, unsigned short* __restrict__ dst,
                                int NT, int K, int total) {
    int u = blockIdx.x * 256 + threadIdx.x;
    if (u >= total) return;
    int l = u & 63; int v = u >> 6; int nt = v % NT; int kt = v / NT;
    int n = nt * 16 + (l & 15);
    int k = kt * 32 + ((l >> 4) << 3);
    const float* s = src + n * K + k;
    float4 s0 = *(const float4*)s;
    float4 s1 = *(const float4*)(s + 4);
    bf16x8 o;
    o[0] = f2bf(s0.x); o[1] = f2bf(s0.y); o[2] = f2bf(s0.z); o[3] = f2bf(s0.w);
    o[4] = f2bf(s1.x); o[5] = f2bf(s1.y); o[6] = f2bf(s1.z); o[7] = f2bf(s1.w);
    *(bf16x8*)(dst + u * 8) = o;
}

// gates B = [W_ih | W_hh] (512 x 192) -> frag order (6 kt x 32 nt)
__global__ void swizzle_cat_kernel(const float* __restrict__ W_ih, const float* __restrict__ W_hh,
                                   unsigned short* __restrict__ dst) {
    int u = blockIdx.x * 256 + threadIdx.x;   // 6*32*64 = 12288 units
    if (u >= 6 * 32 * 64) return;
    int l = u & 63; int v = u >> 6; int nt = v & 31; int kt = v >> 5;
    int n = nt * 16 + (l & 15);
    int k0 = kt * 32 + ((l >> 4) << 3);
    bf16x8 o;
#pragma unroll
    for (int e = 0; e < 8; ++e) {
        int k = k0 + e;
        float val = (k < ED) ? W_ih[n * ED + k] : W_hh[n * HD + (k - ED)];
        o[e] = f2bf(val);
    }
    *(bf16x8*)(dst + u * 8) = o;
}

// u B-matrix = [Wp1_h | 0 | 0 | CV | 0pad] (512 x 160) -> frag order (5 kt x 32 nt)
__global__ void swizzle_p1_kernel(const float* __restrict__ Wp1,
                                  const float* __restrict__ CV,
                                  unsigned short* __restrict__ dst) {
    int u = blockIdx.x * 256 + threadIdx.x;   // 5*32*64 = 10240 units
    if (u >= 5 * 32 * 64) return;
    int l = u & 63; int v = u >> 6; int nt = v & 31; int kt = v >> 5;
    int n = nt * 16 + (l & 15);
    int k0 = kt * 32 + ((l >> 4) << 3);
    bf16x8 o;
#pragma unroll
    for (int e = 0; e < 8; ++e) {
        int k = k0 + e;
        float val;
        if (k < HD)           val = Wp1[n * (ED + HD) + ED + k];
        else if (k == HD + 2) val = CV[n];
        else                  val = 0.f;
        o[e] = f2bf(val);
    }
    *(bf16x8*)(dst + u * 8) = o;
}

// M = Wp1[:, :64] @ Wp_emb  (512x2), cvec = Wp1[:, :64] @ bp_emb + bp1
__global__ void mcvec_kernel(const float* __restrict__ Wp1, const float* __restrict__ Wp_emb,
                             const float* __restrict__ bp_emb, const float* __restrict__ bp1,
                             float* __restrict__ M0, float* __restrict__ M1, float* __restrict__ CV) {
    int r = blockIdx.x * blockDim.x + threadIdx.x;
    if (r >= MIDD) return;
    float m0 = 0.f, m1 = 0.f, cv = 0.f;
    for (int e = 0; e < ED; ++e) {
        float w = Wp1[r * (ED + HD) + e];
        m0 += w * Wp_emb[e * 2 + 0];
        m1 += w * Wp_emb[e * 2 + 1];
        cv += w * bp_emb[e];
    }
    M0[r] = m0; M1[r] = m1; CV[r] = cv + bp1[r];
}

// frag-order fp32 M tables: M0F[(kt*64+lane)*8+e] = M0[kt*32+(lane>>4)*8+e]
__global__ void m01f_kernel(const float* __restrict__ M0, const float* __restrict__ M1,
                            float* __restrict__ M0F, float* __restrict__ M1F) {
    int id = blockIdx.x * 256 + threadIdx.x;   // 16*64*8 = 8192
    if (id >= 16 * 64 * 8) return;
    int e = id & 7;
    int lane = (id >> 3) & 63;
    int kt = id >> 9;
    int k = kt * 32 + ((lane >> 4) << 3) + e;
    M0F[id] = M0[k];
    M1F[id] = M1[k];
}

__global__ void init_kernel(const float* __restrict__ obs_traj, const float* __restrict__ obs_traj_rel,
                            const float* __restrict__ h0, const float* __restrict__ c0,
                            const float* __restrict__ W_emb, const float* __restrict__ b_emb,
                            float* __restrict__ Hb, float* __restrict__ Cb,
                            float* __restrict__ POSb, float* __restrict__ DIN) {
    int b = blockIdx.x;
    int t = threadIdx.x; // 128
    Hb[b * HD + t] = h0[b * HD + t];
    Cb[b * HD + t] = c0[b * HD + t];
    if (t < 2) POSb[b * 2 + t] = obs_traj[((OBS - 1) * B + b) * 2 + t];
    if (t < ED) {
        float rx = obs_traj_rel[((OBS - 1) * B + b) * 2 + 0];
        float ry = obs_traj_rel[((OBS - 1) * B + b) * 2 + 1];
        DIN[b * ED + t] = W_emb[t * 2 + 0] * rx + W_emb[t * 2 + 1] * ry + b_emb[t];
    }
}

// ---------------------------------------------------------------------------
// fused step: [mlp2 of previous step (h = relu(Y1M@Wm2+bm2), in-kernel) or
// h0 load] -> gates MFMA -> LSTM cell -> rel_pos -> POS/DIN update -> u MFMA.
// Block = one scene, 512 thr (8 waves). mlp2's C-layout output maps exactly
// onto the step's per-wave h-column assignment; h passes via LDS (no global
// round trip, no kernel boundary).
// ---------------------------------------------------------------------------
__global__ __launch_bounds__(512) void fused_step_kernel(
    const unsigned short* __restrict__ Y1Mbf, const unsigned short* __restrict__ Wm2F,
    const float* __restrict__ bm2, const float* __restrict__ Hb, int first,
    const unsigned short* __restrict__ WcatF, const float* __restrict__ b_ih,
    const float* __restrict__ b_hh,
    const float* __restrict__ W_pos, const float* __restrict__ b_pos,
    const float* __restrict__ W_emb, const float* __restrict__ b_emb,
    const unsigned short* __restrict__ Wp1F2,
    float* __restrict__ Cb, float* __restrict__ POSb,
    float* __restrict__ DIN, unsigned short* __restrict__ Hbf,
    float* __restrict__ AbF, float* __restrict__ rel_out) {

    __shared__ unsigned short y2f[32 * 64 * 8];  // mlp2 A-frags, 32KB
    __shared__ unsigned short gf[6 * 64 * 8];    // gates A-frags, 6KB
    __shared__ unsigned short a2f[5 * 64 * 8];   // u A-frags, 5KB
    __shared__ float hprev[16 * HD];             // h_prev, 8KB
    __shared__ float hsh[16 * HD];               // h_lstm, 8KB
    __shared__ float relsh[16][4];

    int gsc = blockIdx.x;          // scene
    int t = threadIdx.x;
    int lane = t & 63, w = t >> 6;
    int colid = lane & 15, quad = lane >> 4;

    if (!first) {
        // ---- mlp2 of previous step: h_prev = relu(Y1M @ Wm2.T + bm2) ----
#pragma unroll
        for (int rep = 0; rep < 4; ++rep) {
            int u = rep * 512 + t;           // 0..2047
            int kt = u >> 6, l = u & 63;
            int row = gsc * PP + (l & 15);
            int kl = kt * 32 + ((l >> 4) << 3);
            *(bf16x8*)(y2f + u * 8) = *(const bf16x8*)(Y1Mbf + row * MLPH + kl);
        }
        __syncthreads();
        f32x4 acch = (f32x4)0.f;
        for (int kt = 0; kt < 32; ++kt) {
            bf16x8 af = *(const bf16x8*)(y2f + (kt * 64 + lane) * 8);
            bf16x8 bfr = *(const bf16x8*)(Wm2F + ((kt * 8 + w) * 64 + lane) * 8);
            acch = __builtin_amdgcn_mfma_f32_16x16x32_bf16(af, bfr, acch, 0, 0, 0);
        }
        int hcol = w * 16 + colid;
        float bb = bm2[hcol];
#pragma unroll
        for (int r = 0; r < 4; ++r) {
            int row = quad * 4 + r;
            hprev[row * HD + hcol] = fmaxf(acch[r] + bb, 0.f);
        }
    } else {
        // ---- first step: h_prev = h0 (from Hb) ----
#pragma unroll
        for (int rep = 0; rep < 4; ++rep) {
            int idx = rep * 512 + t;         // 0..2047
            int row = idx >> 7, col = idx & 127;
            hprev[row * HD + col] = Hb[(gsc * PP + row) * HD + col];
        }
    }
    __syncthreads();

    // build gates A-frags: [din(64) | h_prev(128)], K=192 = 6 kt
    if (t < 384) {
        int kt = t >> 6;
        int j = lane & 15;
        int k0 = kt * 32 + ((lane >> 4) << 3);
        float4 x0, x1;
        if (k0 < ED) {
            int b = gsc * PP + j;
            const float4* p = (const float4*)(DIN + b * ED + k0);
            x0 = p[0]; x1 = p[1];
        } else {
            const float4* p = (const float4*)(hprev + j * HD + (k0 - ED));
            x0 = p[0]; x1 = p[1];
        }
        union { bf16x8 v; unsigned u32[4]; } o;
        o.u32[0] = pk2bf(x0.x, x0.y);
        o.u32[1] = pk2bf(x0.z, x0.w);
        o.u32[2] = pk2bf(x1.x, x1.y);
        o.u32[3] = pk2bf(x1.z, x1.w);
        *(bf16x8*)(gf + t * 8) = o.v;
    }
    __syncthreads();

    // gates MFMA
    f32x4 acc[4];
#pragma unroll
    for (int gi = 0; gi < 4; ++gi) acc[gi] = (f32x4)0.f;
#pragma unroll
    for (int kt = 0; kt < 6; ++kt) {
        bf16x8 af = *(const bf16x8*)(gf + (kt * 64 + lane) * 8);
#pragma unroll
        for (int gi = 0; gi < 4; ++gi) {
            bf16x8 bfr = *(const bf16x8*)(WcatF + ((kt * 32 + gi * 8 + w) * 64 + lane) * 8);
            acc[gi] = __builtin_amdgcn_mfma_f32_16x16x32_bf16(af, bfr, acc[gi], 0, 0, 0);
        }
    }
    // LSTM cell, all four gates in-wave
    int hcol = w * 16 + colid;
    float bias[4];
#pragma unroll
    for (int gi = 0; gi < 4; ++gi) {
        int n = (gi * 8 + w) * 16 + colid;
        bias[gi] = b_ih[n] + b_hh[n];
    }
#pragma unroll
    for (int r = 0; r < 4; ++r) {
        int row = quad * 4 + r;
        int b = gsc * PP + row;
        float gI = acc[0][r] + bias[0];
        float gF = acc[1][r] + bias[1];
        float gG = acc[2][r] + bias[2];
        float gO = acc[3][r] + bias[3];
        float c = Cb[b * HD + hcol];
        float cn = (1.f / (1.f + expf(-gF))) * c + (1.f / (1.f + expf(-gI))) * tanhf(gG);
        float hn = (1.f / (1.f + expf(-gO))) * tanhf(cn);
        Cb[b * HD + hcol] = cn;
        Hbf[b * HD + hcol] = (unsigned short)f2bf(hn);
        hsh[row * HD + hcol] = hn;
    }
    __syncthreads();

    // rel_pos: 32 threads per row, shuffle reduce
    {
        int row = t >> 5, kk = t & 31;
        float r0 = 0.f, r1 = 0.f;
#pragma unroll
        for (int q = 0; q < 4; ++q) {
            int k = kk + q * 32;
            float hv = hsh[row * HD + k];
            r0 = fmaf(hv, W_pos[k], r0);
            r1 = fmaf(hv, W_pos[HD + k], r1);
        }
#pragma unroll
        for (int m = 16; m >= 1; m >>= 1) {
            r0 += __shfl_xor(r0, m, 64);
            r1 += __shfl_xor(r1, m, 64);
        }
        if (kk == 0) {
            int b = gsc * PP + row;
            r0 += b_pos[0]; r1 += b_pos[1];
            float px = POSb[b * 2 + 0] + r0;
            float py = POSb[b * 2 + 1] + r1;
            POSb[b * 2 + 0] = px; POSb[b * 2 + 1] = py;
            rel_out[b * 2 + 0] = r0; rel_out[b * 2 + 1] = r1;
            relsh[row][0] = r0; relsh[row][1] = r1; relsh[row][2] = px; relsh[row][3] = py;
        }
    }
    __syncthreads();

    // next dec_in
#pragma unroll
    for (int rep = 0; rep < 2; ++rep) {
        int idx = rep * 512 + t;
        int row = idx >> 6, e = idx & 63;
        int b = gsc * PP + row;
        DIN[b * ED + e] = W_emb[e * 2 + 0] * relsh[row][0] +
                          W_emb[e * 2 + 1] * relsh[row][1] + b_emb[e];
    }
    // u A-frags: [h(128) | 0 | 0 | 1 | 0pad], K=160 = 5 kt
    if (t < 320) {
        int kt = t >> 6;
        int j = lane & 15;
        int k0 = kt * 32 + ((lane >> 4) << 3);
        float e8[8];
#pragma unroll
        for (int e = 0; e < 8; ++e) {
            int k = k0 + e;
            float v;
            if (k < HD)            v = hsh[j * HD + k];
            else if (k == HD + 2)  v = 1.f;
            else                   v = 0.f;
            e8[e] = v;
        }
        union { bf16x8 v; unsigned u32[4]; } o;
        o.u32[0] = pk2bf(e8[0], e8[1]);
        o.u32[1] = pk2bf(e8[2], e8[3]);
        o.u32[2] = pk2bf(e8[4], e8[5]);
        o.u32[3] = pk2bf(e8[6], e8[7]);
        *(bf16x8*)(a2f + t * 8) = o.v;
    }
    __syncthreads();

    // u MFMA: wave w -> nt = w*4+q (512 cols total); write AbF in frag order
    f32x4 acc2[4];
#pragma unroll
    for (int q = 0; q < 4; ++q) acc2[q] = (f32x4)0.f;
#pragma unroll
    for (int kt = 0; kt < 5; ++kt) {
        bf16x8 af = *(const bf16x8*)(a2f + (kt * 64 + lane) * 8);
#pragma unroll
        for (int q = 0; q < 4; ++q) {
            bf16x8 bfr = *(const bf16x8*)(Wp1F2 + ((kt * 32 + w * 4 + q) * 64 + lane) * 8);
            acc2[q] = __builtin_amdgcn_mfma_f32_16x16x32_bf16(af, bfr, acc2[q], 0, 0, 0);
        }
    }
#pragma unroll
    for (int q = 0; q < 4; ++q)
#pragma unroll
        for (int r = 0; r < 4; ++r) {
            int j = quad * 4 + r;                 // row within scene
            int k = (w * 4 + q) * 16 + colid;     // col (k-dim of pool GEMM)
            int kt2 = k >> 5, lk = (k >> 3) & 3, e = k & 7;
            AbF[((gsc * 16 + kt2) * 64 + lk * 16 + j) * 8 + e] = acc2[q][r];
        }
}

// ---------------------------------------------------------------------------
// pool_gemm13: plateaued structure (R9-R14 neutral set), retained.
// ---------------------------------------------------------------------------
__global__ __launch_bounds__(256, 4) void pool_gemm13_kernel(
    const float* __restrict__ AbF, const float* __restrict__ POSb,
    const float* __restrict__ M0F, const float* __restrict__ M1F,
    const unsigned short* __restrict__ Wp2F, const float* __restrict__ bp2,
    unsigned short* __restrict__ POOLbf) {

    __shared__ __align__(16) unsigned short Bst[2][8 * 64 * 8];   // 2 x 8KB
    __shared__ __align__(16) float UMst[2][6][64 * 4];            // 2 x 6KB part-major

    int bi = blockIdx.x;
    int g = bi % 96;                 // scene -> XCD-local
    int rest = bi / 96;              // 0..15
    int io = rest >> 3;              // 0..1
    int colq = rest & 7;             // 0..7
    int t = threadIdx.x, lane = t & 63, w = t >> 6;
    int i0 = io * 8 + w * 2;
    int j = lane & 15;
    int ntb = colq * 8;

    float pjx = POSb[(g * PP + j) * 2 + 0];
    float pjy = POSb[(g * PP + j) * 2 + 1];
    float dx[2], dy[2];
#pragma unroll
    for (int p = 0; p < 2; ++p) {
        int gi = g * PP + i0 + p;
        dx[p] = pjx - POSb[gi * 2 + 0];
        dy[p] = pjy - POSb[gi * 2 + 1];
    }

    const float* ag = AbF + (size_t)g * (16 * 64 * 8);

    auto stage = [&](int kt, int buf) {
#pragma unroll
        for (int r = 0; r < 2; ++r) {
            int u = r * 256 + t;            // 0..511
            int nt = u >> 6, l = u & 63;
            *(bf16x8*)&Bst[buf][u * 8] =
                *(const bf16x8*)(Wp2F + ((kt * 64 + ntb + nt) * 64 + l) * 8);
        }
        {
            int pt = t >> 6;                 // 0..3
            int l = t & 63;
            const float* src = (pt < 2) ? (ag + kt * 512 + l * 8 + pt * 4)
                                        : (M0F + kt * 512 + l * 8 + (pt - 2) * 4);
            *(float4*)&UMst[buf][pt][l * 4] = *(const float4*)src;
            if (t < 128) {
                int pt2 = 4 + (t >> 6);
                *(float4*)&UMst[buf][pt2][l * 4] =
                    *(const float4*)(M1F + kt * 512 + l * 8 + (t >> 6) * 4);
            }
        }
    };

    f32x4 acc[2][8];
#pragma unroll
    for (int p = 0; p < 2; ++p)
#pragma unroll
        for (int n = 0; n < 8; ++n) acc[p][n] = (f32x4)0.f;

    stage(0, 0);
    __syncthreads();

    for (int kt = 0; kt < 16; ++kt) {
        int buf = kt & 1;
        if (kt < 15) stage(kt + 1, buf ^ 1);

        float4 u0  = *(const float4*)&UMst[buf][0][lane * 4];
        float4 u1  = *(const float4*)&UMst[buf][1][lane * 4];
        float4 m00 = *(const float4*)&UMst[buf][2][lane * 4];
        float4 m01 = *(const float4*)&UMst[buf][3][lane * 4];
        float4 m10 = *(const float4*)&UMst[buf][4][lane * 4];
        float4 m11 = *(const float4*)&UMst[buf][5][lane * 4];

        bf16x8 af[2];
#pragma unroll
        for (int p = 0; p < 2; ++p) {
            float dxp = dx[p], dyp = dy[p];
            float r0 = fmaxf(fmaf(m10.x, dyp, fmaf(m00.x, dxp, u0.x)), 0.f);
            float r1 = fmaxf(fmaf(m10.y, dyp, fmaf(m00.y, dxp, u0.y)), 0.f);
            float r2 = fmaxf(fmaf(m10.z, dyp, fmaf(m00.z, dxp, u0.z)), 0.f);
            float r3 = fmaxf(fmaf(m10.w, dyp, fmaf(m00.w, dxp, u0.w)), 0.f);
            float r4 = fmaxf(fmaf(m11.x, dyp, fmaf(m01.x, dxp, u1.x)), 0.f);
            float r5 = fmaxf(fmaf(m11.y, dyp, fmaf(m01.y, dxp, u1.y)), 0.f);
            float r6 = fmaxf(fmaf(m11.z, dyp, fmaf(m01.z, dxp, u1.z)), 0.f);
            float r7 = fmaxf(fmaf(m11.w, dyp, fmaf(m01.w, dxp, u1.w)), 0.f);
            union { bf16x8 v; unsigned u32[4]; } o;
            o.u32[0] = pk2bf(r0, r1);
            o.u32[1] = pk2bf(r2, r3);
            o.u32[2] = pk2bf(r4, r5);
            o.u32[3] = pk2bf(r6, r7);
            af[p] = o.v;
        }
#pragma unroll
        for (int ng = 0; ng < 2; ++ng) {
            bf16x8 bfr[4];
#pragma unroll
            for (int n = 0; n < 4; ++n)
                bfr[n] = *(const bf16x8*)&Bst[buf][((ng * 4 + n) * 64 + lane) * 8];
#pragma unroll
            for (int n = 0; n < 4; ++n) {
                acc[0][ng * 4 + n] =
                    __builtin_amdgcn_mfma_f32_16x16x32_bf16(af[0], bfr[n], acc[0][ng * 4 + n], 0, 0, 0);
                acc[1][ng * 4 + n] =
                    __builtin_amdgcn_mfma_f32_16x16x32_bf16(af[1], bfr[n], acc[1][ng * 4 + n], 0, 0, 0);
            }
        }
        __syncthreads();
    }

    int quad = lane >> 4, colid = lane & 15;
#pragma unroll
    for (int p = 0; p < 2; ++p) {
        int i = g * PP + i0 + p;
#pragma unroll
        for (int n = 0; n < 8; ++n) {
            float m = fmaxf(fmaxf(acc[p][n][0], acc[p][n][1]),
                            fmaxf(acc[p][n][2], acc[p][n][3]));
            m = fmaxf(m, __shfl_xor(m, 16, 64));
            m = fmaxf(m, __shfl_xor(m, 32, 64));
            if (quad == 0) {
                int col = (ntb + n) * 16 + colid;
                float v = fmaxf(m + bp2[col], 0.f);
                POOLbf[i * BOT + col] = (unsigned short)f2bf(v);
            }
        }
    }
}

// ---------------------------------------------------------------------------
// MLP1 (MFMA): [Hbf | POOLbf] (1536x1152) @ Wm1F -> relu -> Y1Mbf (1536x1024)
// ---------------------------------------------------------------------------
__global__ __launch_bounds__(256) void mlp1_mfma_kernel(
    const unsigned short* __restrict__ Hbf, const unsigned short* __restrict__ POOLbf,
    const unsigned short* __restrict__ Wm1F, const float* __restrict__ bm1,
    unsigned short* __restrict__ Y1Mbf) {

    __shared__ unsigned short a_f[16 * 64 * 8];   // 16KB
    int mg = blockIdx.x;       // 0..23
    int ng = blockIdx.y;       // 0..15
    int t = threadIdx.x, lane = t & 63, w = t >> 6;
    int rh = w >> 1, nh = w & 1;

    f32x4 acc[2][2];
#pragma unroll
    for (int a = 0; a < 2; ++a)
#pragma unroll
        for (int b = 0; b < 2; ++b) acc[a][b] = (f32x4)0.f;

    for (int c = 0; c < 9; ++c) {
        __syncthreads();
#pragma unroll
        for (int u0 = 0; u0 < 1024; u0 += 256) {
            int u = u0 + t;
            int rg = u >> 8, kt = (u >> 6) & 3, l = u & 63;
            int row = mg * 64 + rg * 16 + (l & 15);
            int kl = kt * 32 + ((l >> 4) << 3);
            const unsigned short* src = (c == 0) ? (Hbf + row * HD + kl)
                                                 : (POOLbf + row * BOT + (c - 1) * 128 + kl);
            *(bf16x8*)(a_f + u * 8) = *(const bf16x8*)src;
        }
        __syncthreads();
#pragma unroll
        for (int kt = 0; kt < 4; ++kt) {
            int ktg = c * 4 + kt;
            bf16x8 bfr[2];
#pragma unroll
            for (int j = 0; j < 2; ++j) {
                int ntg = ng * 4 + nh * 2 + j;
                bfr[j] = *(const bf16x8*)(Wm1F + ((ktg * 64 + ntg) * 64 + lane) * 8);
            }
#pragma unroll
            for (int ri = 0; ri < 2; ++ri) {
                int rg = rh * 2 + ri;
                bf16x8 af = *(const bf16x8*)(a_f + ((rg * 4 + kt) * 64 + lane) * 8);
#pragma unroll
                for (int j = 0; j < 2; ++j)
                    acc[ri][j] = __builtin_amdgcn_mfma_f32_16x16x32_bf16(af, bfr[j], acc[ri][j], 0, 0, 0);
            }
        }
    }
    int quad = lane >> 4, colid = lane & 15;
#pragma unroll
    for (int ri = 0; ri < 2; ++ri)
#pragma unroll
        for (int j = 0; j < 2; ++j) {
            int col = ng * 64 + (nh * 2 + j) * 16 + colid;
            float bb = bm1[col];
#pragma unroll
            for (int r = 0; r < 4; ++r) {
                int row = mg * 64 + (rh * 2 + ri) * 16 + quad * 4 + r;
                float v = fmaxf(acc[ri][j][r] + bb, 0.f);
                Y1Mbf[row * MLPH + col] = (unsigned short)f2bf(v);
            }
        }
}

// ---------------------------------------------------------------------------
// MLP2 standalone (final step only): Y1Mbf @ Wm2F -> relu -> h_out
// ---------------------------------------------------------------------------
__global__ __launch_bounds__(256) void mlp2_mfma_kernel(
    const unsigned short* __restrict__ Y1Mbf, const unsigned short* __restrict__ Wm2F,
    const float* __restrict__ bm2, float* __restrict__ hout) {

    __shared__ unsigned short a_f[32 * 64 * 8];   // 32KB
    int rg = blockIdx.x;   // 0..95
    int t = threadIdx.x, lane = t & 63, w = t >> 6;

#pragma unroll
    for (int u0 = 0; u0 < 2048; u0 += 256) {
        int u = u0 + t;
        int kt = u >> 6, l = u & 63;
        int row = rg * 16 + (l & 15);
        int kl = kt * 32 + ((l >> 4) << 3);
        *(bf16x8*)(a_f + u * 8) = *(const bf16x8*)(Y1Mbf + row * MLPH + kl);
    }
    __syncthreads();

    f32x4 acc[2];
    acc[0] = (f32x4)0.f; acc[1] = (f32x4)0.f;
    for (int kt = 0; kt < 32; ++kt) {
        bf16x8 af = *(const bf16x8*)(a_f + (kt * 64 + lane) * 8);
#pragma unroll
        for (int j = 0; j < 2; ++j) {
            int ntg = w * 2 + j;
            bf16x8 bfr = *(const bf16x8*)(Wm2F + ((kt * 8 + ntg) * 64 + lane) * 8);
            acc[j] = __builtin_amdgcn_mfma_f32_16x16x32_bf16(af, bfr, acc[j], 0, 0, 0);
        }
    }
    int quad = lane >> 4, colid = lane & 15;
#pragma unroll
    for (int j = 0; j < 2; ++j) {
        int col = (w * 2 + j) * 16 + colid;
        float bb = bm2[col];
#pragma unroll
        for (int r = 0; r < 4; ++r) {
            int row = rg * 16 + quad * 4 + r;
            hout[row * HD + col] = fmaxf(acc[j][r] + bb, 0.f);
        }
    }
}

// ---------------------------------------------------------------------------
extern "C" void kernel_launch(void* const* d_in, const int* in_sizes, int n_in,
                              void* d_out, int out_size, void* d_ws, size_t ws_size,
                              hipStream_t stream) {
    const float* obs_traj     = (const float*)d_in[0];
    const float* obs_traj_rel = (const float*)d_in[1];
    const float* h0    = (const float*)d_in[3];
    const float* c0    = (const float*)d_in[4];
    const float* W_emb = (const float*)d_in[6];
    const float* b_emb = (const float*)d_in[7];
    const float* W_ih  = (const float*)d_in[8];
    const float* b_ih  = (const float*)d_in[9];
    const float* W_hh  = (const float*)d_in[10];
    const float* b_hh  = (const float*)d_in[11];
    const float* W_pos = (const float*)d_in[12];
    const float* b_pos = (const float*)d_in[13];
    const float* Wp_emb= (const float*)d_in[14];
    const float* bp_emb= (const float*)d_in[15];
    const float* Wp1   = (const float*)d_in[16];
    const float* bp1   = (const float*)d_in[17];
    const float* Wp2   = (const float*)d_in[18];
    const float* bp2   = (const float*)d_in[19];
    const float* Wm1   = (const float*)d_in[20];
    const float* bm1   = (const float*)d_in[21];
    const float* Wm2   = (const float*)d_in[22];
    const float* bm2   = (const float*)d_in[23];

    float* ws = (float*)d_ws;
    float* Hb    = ws; ws += B * HD;
    float* Cb    = ws; ws += B * HD;
    float* POSb  = ws; ws += B * 2;
    float* DIN   = ws; ws += B * ED;
    float* AbF   = ws; ws += B * MIDD;   // frag-order u (96 scenes x 16kt x 64 x 8)
    float* M0    = ws; ws += MIDD;
    float* M1    = ws; ws += MIDD;
    float* CV    = ws; ws += MIDD;
    float* M0F   = ws; ws += 16 * 64 * 8;
    float* M1F   = ws; ws += 16 * 64 * 8;
    unsigned short* us = (unsigned short*)ws;
    unsigned short* Hbf    = us; us += B * HD;
    unsigned short* POOLbf = us; us += B * BOT;
    unsigned short* Y1Mbf  = us; us += B * MLPH;
    unsigned short* WcatF  = us; us += 6 * 32 * 64 * 8;
    unsigned short* Wp1F2  = us; us += 5 * 32 * 64 * 8;
    unsigned short* Wp2F   = us; us += MIDD * BOT;
    unsigned short* Wm1F   = us; us += CTXD * MLPH;
    unsigned short* Wm2F   = us; us += MLPH * HD;

    float* out = (float*)d_out;
    float* rels_out = out;                 // (12,1536,2)
    float* h_out    = out + SEQL * B * 2;  // (1536,128)

    // setup
    {
        int tot = 16 * 64 * 64;   // Wp2: K=512, NT=64
        swizzleB_kernel<<<(tot + 255) / 256, 256, 0, stream>>>(Wp2, Wp2F, 64, MIDD, tot);
        tot = 36 * 64 * 64;       // Wm1: K=1152, NT=64
        swizzleB_kernel<<<(tot + 255) / 256, 256, 0, stream>>>(Wm1, Wm1F, 64, CTXD, tot);
        tot = 32 * 8 * 64;        // Wm2: K=1024, NT=8
        swizzleB_kernel<<<(tot + 255) / 256, 256, 0, stream>>>(Wm2, Wm2F, 8, MLPH, tot);
        swizzle_cat_kernel<<<(6 * 32 * 64 + 255) / 256, 256, 0, stream>>>(W_ih, W_hh, WcatF);
    }
    mcvec_kernel<<<2, 256, 0, stream>>>(Wp1, Wp_emb, bp_emb, bp1, M0, M1, CV);
    swizzle_p1_kernel<<<(5 * 32 * 64 + 255) / 256, 256, 0, stream>>>(Wp1, CV, Wp1F2);
    m01f_kernel<<<32, 256, 0, stream>>>(M0, M1, M0F, M1F);
    init_kernel<<<B, 128, 0, stream>>>(obs_traj, obs_traj_rel, h0, c0, W_emb, b_emb,
                                       Hb, Cb, POSb, DIN);

    for (int s = 0; s < SEQL; ++s) {
        fused_step_kernel<<<G, 512, 0, stream>>>(
            Y1Mbf, Wm2F, bm2, Hb, (s == 0) ? 1 : 0,
            WcatF, b_ih, b_hh, W_pos, b_pos, W_emb, b_emb, Wp1F2,
            Cb, POSb, DIN, Hbf, AbF, rels_out + s * B * 2);
        pool_gemm13_kernel<<<G * 16, 256, 0, stream>>>(AbF, POSb, M0F, M1F, Wp2F, bp2, POOLbf);
        mlp1_mfma_kernel<<<dim3(24, 16), 256, 0, stream>>>(Hbf, POOLbf, Wm1F, bm1, Y1Mbf);
    }
    mlp2_mfma_kernel<<<G, 256, 0, stream>>>(Y1Mbf, Wm2F, bm2, h_out);
}